// Round 7
// baseline (6886.742 us; speedup 1.0000x reference)
//
#include <hip/hip_runtime.h>

// B=16, T=256, IN=256, H=1024, L=4, 4 gates -> 4H=4096.
// R10 = R9 (proven, 6853us) + occupancy-guarded layer-pair wavefront.
//   - lstm_pair runs layers (A,B) in one persistent kernel, pipelined:
//     step s = A-scan(t=s) + B-pre(t'=s-1, hA @ WxB, 3-term/5-pass, reg-
//     resident Wx, result in LDS ring) + B-scan(t1=s-2). 2*258 steps vs 1024,
//     2 pre_gemms vs 4. Protocol = R9's flattened per-group counters, two
//     planes (A,B) polled by wave-0 lanes 0-15 / 16-31.
//   - HOST-side hipOccupancyMaxActiveBlocksPerMultiprocessor query (capture-
//     safe) decides at capture time: pair path iff >=1 block/CU; else the
//     EXACT R9 path. (R4-R8 evidence: oversized cooperative kernels are
//     silently rejected at enqueue -> output never written. Never enqueue
//     a launch that can fail.)
//   - bounded spin (1<<14) + dead-latch: protocol bug => fast wrong answer.
//
// ws (114.1 MB): pre 16,777,216 f | seqA 4,194,304 f
//   | reg2 4,194,304 f  (fallback: seqB | pair: hBhi+hBlo u16 planes)
//   | hAhi/hAlo 4,194,304 u16 each | ctr 528,384 ints

typedef float f32x4 __attribute__((ext_vector_type(4)));
typedef short bf16x8 __attribute__((ext_vector_type(8)));

__device__ __forceinline__ unsigned short f2bf_rn(float x) {
    unsigned int u = __float_as_uint(x);
    u += 0x7FFFu + ((u >> 16) & 1u);          // round-to-nearest-even
    return (unsigned short)(u >> 16);
}
__device__ __forceinline__ float bf2f(unsigned short s) {
    return __uint_as_float(((unsigned int)s) << 16);
}
__device__ __forceinline__ float sigmoidf_(float x) { return 1.0f / (1.0f + __expf(-x)); }
__device__ __forceinline__ float tanhf_(float x) {
    float e = __expf(2.0f * x);
    return 1.0f - 2.0f / (e + 1.0f);
}

#define MFMA16(a, b, c) __builtin_amdgcn_mfma_f32_16x16x32_bf16((a), (b), (c), 0, 0, 0)

// ---------------------------------------------------------------------------
// pre GEMM (proven, unchanged): 128x128 tile, BK=16, fp32.
// ---------------------------------------------------------------------------
__global__ __launch_bounds__(256)
void pre_gemm(const float* __restrict__ A, const float* __restrict__ W,
              const float* __restrict__ bias, float* __restrict__ out, int K)
{
    __shared__ float As[16][132];
    __shared__ float Bs[16][132];

    const int tid = threadIdx.x;
    const int m0 = blockIdx.y << 7;
    const int n0 = blockIdx.x << 7;
    const int g  = n0 >> 10;
    const int jb = n0 & 1023;
    const float* Wg = W + (size_t)g * K * 1024 + jb;

    const int tx = tid & 15;
    const int ty = tid >> 4;
    const int alk = tid & 15;
    const int alm = tid >> 4;
    const int bln = tid & 127;
    const int blkk = tid >> 7;

    float acc[8][8];
#pragma unroll
    for (int i = 0; i < 8; ++i)
#pragma unroll
        for (int j = 0; j < 8; ++j) acc[i][j] = 0.f;

    for (int k0 = 0; k0 < K; k0 += 16) {
        __syncthreads();
#pragma unroll
        for (int r = 0; r < 8; ++r) {
            int m = alm + (r << 4);
            As[alk][m] = A[(size_t)(m0 + m) * K + (k0 + alk)];
        }
#pragma unroll
        for (int r = 0; r < 8; ++r) {
            int kk = blkk + (r << 1);
            Bs[kk][bln] = Wg[(size_t)(k0 + kk) * 1024 + bln];
        }
        __syncthreads();
#pragma unroll
        for (int k = 0; k < 16; ++k) {
            float a[8], bb[8];
            *(f32x4*)&a[0]  = *(const f32x4*)&As[k][ty << 2];
            *(f32x4*)&a[4]  = *(const f32x4*)&As[k][64 + (ty << 2)];
            *(f32x4*)&bb[0] = *(const f32x4*)&Bs[k][tx << 2];
            *(f32x4*)&bb[4] = *(const f32x4*)&Bs[k][64 + (tx << 2)];
#pragma unroll
            for (int i = 0; i < 8; ++i)
#pragma unroll
                for (int j = 0; j < 8; ++j)
                    acc[i][j] = fmaf(a[i], bb[j], acc[i][j]);
        }
    }

    float bj[8];
#pragma unroll
    for (int j = 0; j < 8; ++j) {
        int nloc = (j < 4) ? ((tx << 2) + j) : (64 + (tx << 2) + (j - 4));
        bj[j] = bias[n0 + nloc];
    }
#pragma unroll
    for (int i = 0; i < 8; ++i) {
        int mloc = (i < 4) ? ((ty << 2) + i) : (64 + (ty << 2) + (i - 4));
        int m = m0 + mloc;
        int bidx = m >> 8;
        int tt   = m & 255;
        float* orow = out + ((size_t)((tt << 4) + bidx) << 12) + n0;
#pragma unroll
        for (int j = 0; j < 8; ++j) {
            int nloc = (j < 4) ? ((tx << 2) + j) : (64 + (tx << 2) + (j - 4));
            orow[nloc] = acc[i][j] + bj[j];
        }
    }
}

// ---------------------------------------------------------------------------
// R9 single-layer scan (proven at 6853us total). VERBATIM fallback.
// ---------------------------------------------------------------------------
__global__ __launch_bounds__(256)
void lstm_scan(const float* __restrict__ pre,
               const float* __restrict__ Wh,
               float* __restrict__ seq_out,
               unsigned short* __restrict__ hhi,
               unsigned short* __restrict__ hlo,
               int* __restrict__ ctr_l1,
               float* __restrict__ final_out,
               int is_last)
{
    const int wg   = blockIdx.x;
    const int tid  = threadIdx.x;
    const int wv   = tid >> 6;
    const int lane = tid & 63;
    const int bc   = lane & 15;
    const int quad = lane >> 4;

    __shared__ float red[4][64][4];
    __shared__ float gsh[16][17];

    const int g   = bc >> 2;
    const int col = (wg << 2) + (bc & 3);
    bf16x8 Whi[8], Wmi[8], Wlo[8];
#pragma unroll
    for (int ck = 0; ck < 8; ++ck) {
#pragma unroll
        for (int j = 0; j < 8; ++j) {
            int k = (wv << 8) + (ck << 5) + (quad << 3) + j;
            float w = Wh[((size_t)g << 20) + ((size_t)k << 10) + col];
            unsigned short hi = f2bf_rn(w);
            float r1 = w - bf2f(hi);
            unsigned short mi = f2bf_rn(r1);
            float r2 = r1 - bf2f(mi);
            unsigned short lo = f2bf_rn(r2);
            Whi[ck][j] = (short)hi;
            Wmi[ck][j] = (short)mi;
            Wlo[ck][j] = (short)lo;
        }
    }

    float creg = 0.f;
    int dead = 0;

    for (int t = 0; t < 256; ++t) {
        float pr[4];
        if (wv == 0) {
            const float* pp = pre + ((size_t)t << 16) + ((size_t)(bc >> 2) << 10)
                              + (wg << 2) + (bc & 3);
#pragma unroll
            for (int r = 0; r < 4; ++r)
                pr[r] = pp[(size_t)((quad << 2) + r) << 12];
        }

        if (t > 0 && wv == 0 && !dead) {
            const int* lb = ctr_l1 + (((t - 1) << 4) << 5);
            bool done = (lane >= 16);
            const int gi5 = (lane & 15) << 5;
            int guard = 0;
            for (;;) {
                if (!done)
                    done = __hip_atomic_load(lb + gi5, __ATOMIC_RELAXED,
                                             __HIP_MEMORY_SCOPE_AGENT) >= 16;
                if (__all(done)) break;
                __builtin_amdgcn_s_sleep(1);
                if (++guard > (1 << 15)) { dead = 1; break; }
            }
        }
        __syncthreads();
        asm volatile("" ::: "memory");

        f32x4 a00 = {0.f, 0.f, 0.f, 0.f};
        f32x4 a01 = a00, a10 = a00, a11 = a00;
        if (t > 0) {
            const size_t pb = ((size_t)(t - 1) << 14) + ((size_t)bc << 10) + (wv << 8);
            const unsigned short* ph = hhi + pb;
            const unsigned short* pl = hlo + pb;
            bf16x8 ahi[8], alo[8];
#pragma unroll
            for (int ck = 0; ck < 8; ++ck) {
                ahi[ck] = *(const bf16x8*)(ph + (ck << 5) + (quad << 3));
                alo[ck] = *(const bf16x8*)(pl + (ck << 5) + (quad << 3));
            }
#pragma unroll
            for (int ck = 0; ck < 8; ++ck) {
                if (ck & 1) {
                    a10 = MFMA16(ahi[ck], Whi[ck], a10);
                    a11 = MFMA16(ahi[ck], Wmi[ck], a11);
                    a10 = MFMA16(ahi[ck], Wlo[ck], a10);
                    a11 = MFMA16(alo[ck], Whi[ck], a11);
                    a10 = MFMA16(alo[ck], Wmi[ck], a10);
                } else {
                    a00 = MFMA16(ahi[ck], Whi[ck], a00);
                    a01 = MFMA16(ahi[ck], Wmi[ck], a01);
                    a00 = MFMA16(ahi[ck], Wlo[ck], a00);
                    a01 = MFMA16(alo[ck], Whi[ck], a01);
                    a00 = MFMA16(alo[ck], Wmi[ck], a00);
                }
            }
        }
        f32x4 acc = (a00 + a01) + (a10 + a11);
        *(f32x4*)&red[wv][lane][0] = acc;
        __syncthreads();

        if (wv == 0) {
            f32x4 s0 = *(const f32x4*)&red[0][lane][0];
            f32x4 s1 = *(const f32x4*)&red[1][lane][0];
            f32x4 s2 = *(const f32x4*)&red[2][lane][0];
            f32x4 s3 = *(const f32x4*)&red[3][lane][0];
            f32x4 s = (s0 + s1) + (s2 + s3);
#pragma unroll
            for (int r = 0; r < 4; ++r)
                gsh[(quad << 2) + r][bc] = s[r] + pr[r];

            const int b2 = lane >> 2, jl2 = lane & 3;
            float fg = sigmoidf_(gsh[b2][jl2]);
            float ig = sigmoidf_(gsh[b2][4 + jl2]);
            float pg = tanhf_(gsh[b2][8 + jl2]);
            float og = sigmoidf_(gsh[b2][12 + jl2]);
            creg = fg * creg + ig * pg;
            float h = tanhf_(creg) * og;

            const int j = (wg << 2) + jl2;
            unsigned short hh = f2bf_rn(h);
            unsigned short hl = f2bf_rn(h - bf2f(hh));
            size_t pidx = ((size_t)t << 14) + ((size_t)b2 << 10) + j;
            __hip_atomic_store(&hhi[pidx], hh, __ATOMIC_RELAXED, __HIP_MEMORY_SCOPE_AGENT);
            __hip_atomic_store(&hlo[pidx], hl, __ATOMIC_RELAXED, __HIP_MEMORY_SCOPE_AGENT);
            if (is_last && t == 255) final_out[((size_t)b2 << 10) + j] = h;

            __builtin_amdgcn_s_waitcnt(0);
            if (lane == 0)
                __hip_atomic_fetch_add(&ctr_l1[((t << 4) + (wg >> 4)) << 5], 1,
                                       __ATOMIC_RELAXED,
                                       __HIP_MEMORY_SCOPE_AGENT);

            if (!is_last)
                seq_out[((size_t)((b2 << 8) + t) << 10) + j] = h;
        }
    }
}

// ---------------------------------------------------------------------------
// Layer-pair wavefront. 256 wgs x 256 threads, R9 protocol x2 flag planes.
// Step s: [A-scan t=s | B-pre t'=s-1 | B-scan t1=s-2], 2 barriers.
// wave0 finish: A gates -> hA stores -> drain -> ctrA[s]. wave1: B gates ->
// hB stores -> drain -> ctrB[s] (-> seq/final off-drain). wave2: B-pre ring.
// A/B fragments streamed per-ck to hold VGPR use under the spill line.
// ---------------------------------------------------------------------------
__global__ __launch_bounds__(256)
void lstm_pair(const float* __restrict__ preA,   // [256][16][4096]
               const float* __restrict__ WhA,    // [4][1024][1024]
               const float* __restrict__ WhB,    // [4][1024][1024]
               const float* __restrict__ WxB,    // [4][1024][1024]
               const float* __restrict__ biasB,  // [4][1024]
               float* __restrict__ seq_out,      // [16][256][1024] (!is_last)
               unsigned short* __restrict__ hAhi, unsigned short* __restrict__ hAlo,
               unsigned short* __restrict__ hBhi, unsigned short* __restrict__ hBlo,
               int* __restrict__ ctrA,           // [258 s][16 grp] stride-32
               int* __restrict__ ctrB,           // [258 s][16 grp] stride-32
               float* __restrict__ final_out,    // [16][1024]
               int is_last)
{
    const int wg   = blockIdx.x;
    const int tid  = threadIdx.x;
    const int wv   = tid >> 6;
    const int lane = tid & 63;
    const int bc   = lane & 15;
    const int quad = lane >> 4;

    __shared__ float red[3][4][64][4]; // [A | B-pre | B-scan] reductions
    __shared__ float gsh[2][16][17];   // gate exchange [A/B][b][g*4+jl]
    __shared__ float ring[2][16][17];  // B-pre ring: preB[k] in slot k&1

    const int g   = bc >> 2;
    const int col = (wg << 2) + (bc & 3);

    // one-time: 3-term bf16 splits of WhA, WhB, WxB (288 regs, AGPR-eligible)
    bf16x8 WAh[8], WAm[8], WAl[8];
    bf16x8 WBh[8], WBm[8], WBl[8];
    bf16x8 WXh[8], WXm[8], WXl[8];
#pragma unroll
    for (int ck = 0; ck < 8; ++ck) {
#pragma unroll
        for (int j = 0; j < 8; ++j) {
            const int k = (wv << 8) + (ck << 5) + (quad << 3) + j;
            const size_t widx = ((size_t)g << 20) + ((size_t)k << 10) + col;
            {
                float w = WhA[widx];
                unsigned short hi = f2bf_rn(w); float r1 = w - bf2f(hi);
                unsigned short mi = f2bf_rn(r1); float r2 = r1 - bf2f(mi);
                WAh[ck][j] = (short)hi; WAm[ck][j] = (short)mi;
                WAl[ck][j] = (short)f2bf_rn(r2);
            }
            {
                float w = WhB[widx];
                unsigned short hi = f2bf_rn(w); float r1 = w - bf2f(hi);
                unsigned short mi = f2bf_rn(r1); float r2 = r1 - bf2f(mi);
                WBh[ck][j] = (short)hi; WBm[ck][j] = (short)mi;
                WBl[ck][j] = (short)f2bf_rn(r2);
            }
            {
                float w = WxB[widx];
                unsigned short hi = f2bf_rn(w); float r1 = w - bf2f(hi);
                unsigned short mi = f2bf_rn(r1); float r2 = r1 - bf2f(mi);
                WXh[ck][j] = (short)hi; WXm[ck][j] = (short)mi;
                WXl[ck][j] = (short)f2bf_rn(r2);
            }
        }
    }
    const float biasv = biasB[((size_t)g << 10) + col];

    float creg = 0.f;   // wave0 lanes: layer-A cell; wave1 lanes: layer-B cell
    int dead = 0;

    for (int s = 0; s < 258; ++s) {
        float pr[4];
        if (wv == 0 && s < 256) {
            const float* pp = preA + ((size_t)s << 16) + ((size_t)g << 10) + col;
#pragma unroll
            for (int r = 0; r < 4; ++r)
                pr[r] = pp[(size_t)((quad << 2) + r) << 12];
        }

        if (s > 0 && wv == 0 && !dead) {
            // lanes 0-15: ctrA[s-1][grp] (exists for s<=256);
            // lanes 16-31: ctrB[s-1][grp] (exists for s>=3); others done.
            bool done;
            const int gi = lane & 15;
            const int* wp;
            if (lane < 16)      { done = (s > 256); wp = ctrA + (((s - 1) << 4) + gi) * 32; }
            else if (lane < 32) { done = (s < 3);   wp = ctrB + (((s - 1) << 4) + gi) * 32; }
            else                { done = true;      wp = ctrA; }
            int guard = 0;
            for (;;) {
                if (!done)
                    done = __hip_atomic_load(wp, __ATOMIC_RELAXED,
                                             __HIP_MEMORY_SCOPE_AGENT) >= 16;
                if (__all(done)) break;
                __builtin_amdgcn_s_sleep(1);
                if (++guard > (1 << 14)) { dead = 1; break; }  // bug -> fast wrong answer
            }
        }
        __syncthreads();
        asm volatile("" ::: "memory");

        f32x4 aA0 = {0.f, 0.f, 0.f, 0.f}, aA1 = aA0;
        f32x4 aP0 = aA0, aP1 = aA0;
        f32x4 aB0 = aA0, aB1 = aA0;

        if (s >= 1 && s <= 256) {            // consume hA(s-1): A-scan + B-pre
            const size_t pb = ((size_t)(s - 1) << 14) + ((size_t)bc << 10) + (wv << 8);
            const unsigned short* ph = hAhi + pb;
            const unsigned short* pl = hAlo + pb;
#pragma unroll
            for (int ck = 0; ck < 8; ++ck) {   // streamed frags (VGPR diet)
                bf16x8 ah = *(const bf16x8*)(ph + (ck << 5) + (quad << 3));
                bf16x8 al = *(const bf16x8*)(pl + (ck << 5) + (quad << 3));
                if (ck & 1) {
                    aA1 = MFMA16(ah, WAh[ck], aA1);
                    aA1 = MFMA16(ah, WAm[ck], aA1);
                    aA1 = MFMA16(ah, WAl[ck], aA1);
                    aA1 = MFMA16(al, WAh[ck], aA1);
                    aA1 = MFMA16(al, WAm[ck], aA1);
                    aP1 = MFMA16(ah, WXh[ck], aP1);
                    aP1 = MFMA16(ah, WXm[ck], aP1);
                    aP1 = MFMA16(ah, WXl[ck], aP1);
                    aP1 = MFMA16(al, WXh[ck], aP1);
                    aP1 = MFMA16(al, WXm[ck], aP1);
                } else {
                    aA0 = MFMA16(ah, WAh[ck], aA0);
                    aA0 = MFMA16(ah, WAm[ck], aA0);
                    aA0 = MFMA16(ah, WAl[ck], aA0);
                    aA0 = MFMA16(al, WAh[ck], aA0);
                    aA0 = MFMA16(al, WAm[ck], aA0);
                    aP0 = MFMA16(ah, WXh[ck], aP0);
                    aP0 = MFMA16(ah, WXm[ck], aP0);
                    aP0 = MFMA16(ah, WXl[ck], aP0);
                    aP0 = MFMA16(al, WXh[ck], aP0);
                    aP0 = MFMA16(al, WXm[ck], aP0);
                }
            }
        }
        if (s >= 3) {                        // consume hB(s-3): B-scan
            const size_t pb = ((size_t)(s - 3) << 14) + ((size_t)bc << 10) + (wv << 8);
            const unsigned short* ph = hBhi + pb;
            const unsigned short* pl = hBlo + pb;
#pragma unroll
            for (int ck = 0; ck < 8; ++ck) {
                bf16x8 bh = *(const bf16x8*)(ph + (ck << 5) + (quad << 3));
                bf16x8 bl = *(const bf16x8*)(pl + (ck << 5) + (quad << 3));
                if (ck & 1) {
                    aB1 = MFMA16(bh, WBh[ck], aB1);
                    aB1 = MFMA16(bh, WBm[ck], aB1);
                    aB1 = MFMA16(bh, WBl[ck], aB1);
                    aB1 = MFMA16(bl, WBh[ck], aB1);
                    aB1 = MFMA16(bl, WBm[ck], aB1);
                } else {
                    aB0 = MFMA16(bh, WBh[ck], aB0);
                    aB0 = MFMA16(bh, WBm[ck], aB0);
                    aB0 = MFMA16(bh, WBl[ck], aB0);
                    aB0 = MFMA16(bl, WBh[ck], aB0);
                    aB0 = MFMA16(bl, WBm[ck], aB0);
                }
            }
        }

        *(f32x4*)&red[0][wv][lane][0] = aA0 + aA1;
        *(f32x4*)&red[1][wv][lane][0] = aP0 + aP1;
        *(f32x4*)&red[2][wv][lane][0] = aB0 + aB1;
        __syncthreads();

        if (wv == 0) {
            if (s <= 255) {                                  // layer A, t = s
                f32x4 s0 = *(const f32x4*)&red[0][0][lane][0];
                f32x4 s1 = *(const f32x4*)&red[0][1][lane][0];
                f32x4 s2 = *(const f32x4*)&red[0][2][lane][0];
                f32x4 s3 = *(const f32x4*)&red[0][3][lane][0];
                f32x4 sm = (s0 + s1) + (s2 + s3);
#pragma unroll
                for (int r = 0; r < 4; ++r)
                    gsh[0][(quad << 2) + r][bc] = sm[r] + pr[r];

                const int b2 = lane >> 2, jl2 = lane & 3;
                float fg = sigmoidf_(gsh[0][b2][jl2]);
                float ig = sigmoidf_(gsh[0][b2][4 + jl2]);
                float pg = tanhf_(gsh[0][b2][8 + jl2]);
                float og = sigmoidf_(gsh[0][b2][12 + jl2]);
                creg = fg * creg + ig * pg;
                float h = tanhf_(creg) * og;
                const int j = (wg << 2) + jl2;
                unsigned short hh = f2bf_rn(h);
                unsigned short hl = f2bf_rn(h - bf2f(hh));
                size_t pidx = ((size_t)s << 14) + ((size_t)b2 << 10) + j;
                __hip_atomic_store(&hAhi[pidx], hh, __ATOMIC_RELAXED, __HIP_MEMORY_SCOPE_AGENT);
                __hip_atomic_store(&hAlo[pidx], hl, __ATOMIC_RELAXED, __HIP_MEMORY_SCOPE_AGENT);
                __builtin_amdgcn_s_waitcnt(0);
                if (lane == 0)
                    __hip_atomic_fetch_add(&ctrA[((s << 4) + (wg >> 4)) << 5], 1,
                                           __ATOMIC_RELAXED,
                                           __HIP_MEMORY_SCOPE_AGENT);
            }
        } else if (wv == 1) {
            if (s >= 2) {                                    // layer B, t1 = s-2
                const int t1 = s - 2;
                f32x4 s0 = *(const f32x4*)&red[2][0][lane][0];
                f32x4 s1 = *(const f32x4*)&red[2][1][lane][0];
                f32x4 s2 = *(const f32x4*)&red[2][2][lane][0];
                f32x4 s3 = *(const f32x4*)&red[2][3][lane][0];
                f32x4 sm = (s0 + s1) + (s2 + s3);
#pragma unroll
                for (int r = 0; r < 4; ++r)
                    gsh[1][(quad << 2) + r][bc] =
                        sm[r] + ring[t1 & 1][(quad << 2) + r][bc];

                const int b2 = lane >> 2, jl2 = lane & 3;
                float fg = sigmoidf_(gsh[1][b2][jl2]);
                float ig = sigmoidf_(gsh[1][b2][4 + jl2]);
                float pg = tanhf_(gsh[1][b2][8 + jl2]);
                float og = sigmoidf_(gsh[1][b2][12 + jl2]);
                creg = fg * creg + ig * pg;
                float h = tanhf_(creg) * og;
                const int j = (wg << 2) + jl2;
                unsigned short hh = f2bf_rn(h);
                unsigned short hl = f2bf_rn(h - bf2f(hh));
                size_t pidx = ((size_t)t1 << 14) + ((size_t)b2 << 10) + j;
                __hip_atomic_store(&hBhi[pidx], hh, __ATOMIC_RELAXED, __HIP_MEMORY_SCOPE_AGENT);
                __hip_atomic_store(&hBlo[pidx], hl, __ATOMIC_RELAXED, __HIP_MEMORY_SCOPE_AGENT);
                __builtin_amdgcn_s_waitcnt(0);
                if (lane == 0)
                    __hip_atomic_fetch_add(&ctrB[((s << 4) + (wg >> 4)) << 5], 1,
                                           __ATOMIC_RELAXED,
                                           __HIP_MEMORY_SCOPE_AGENT);
                if (!is_last)
                    seq_out[((size_t)((b2 << 8) + t1) << 10) + j] = h;   // next dispatch
                if (is_last && t1 == 255)
                    final_out[((size_t)b2 << 10) + j] = h;
            }
        } else if (wv == 2) {
            if (s >= 1 && s <= 256) {                        // B-pre for t' = s-1
                f32x4 q0 = *(const f32x4*)&red[1][0][lane][0];
                f32x4 q1 = *(const f32x4*)&red[1][1][lane][0];
                f32x4 q2 = *(const f32x4*)&red[1][2][lane][0];
                f32x4 q3 = *(const f32x4*)&red[1][3][lane][0];
                f32x4 qm = (q0 + q1) + (q2 + q3);
#pragma unroll
                for (int r = 0; r < 4; ++r)
                    ring[(s - 1) & 1][(quad << 2) + r][bc] = qm[r] + biasv;
            }
        }
    }
}

// ---------------------------------------------------------------------------
extern "C" void kernel_launch(void* const* d_in, const int* in_sizes, int n_in,
                              void* d_out, int out_size, void* d_ws, size_t ws_size,
                              hipStream_t stream)
{
    (void)in_sizes; (void)n_in; (void)out_size; (void)ws_size;

    const float* x    = (const float*)d_in[0];   // [16][256][256]
    const float* Wh   = (const float*)d_in[1];   // [4][4][1024][1024]
    const float* Wx0  = (const float*)d_in[2];   // [4][256][1024]
    const float* Wx   = (const float*)d_in[3];   // [3][4][1024][1024]
    const float* bias = (const float*)d_in[4];   // [4][4][1024]

    float* pre  = (float*)d_ws;                    // 16,777,216 f
    float* seqA = pre + 16777216;                  // 4,194,304 f
    float* reg2 = seqA + 4194304;                  // 4,194,304 f (aliased)
    unsigned short* hAhi = (unsigned short*)(reg2 + 4194304);  // 4,194,304 u16
    unsigned short* hAlo = hAhi + 4194304;                     // 4,194,304 u16
    int* ctr = (int*)(hAlo + 4194304);
    // pair: 2 dispatches x 2 planes x 258x16x32 = 528,384 ints (covers
    // fallback's 4 x 256x16x32 = 524,288 too)
    const size_t PAIR_PL = 258 * 16 * 32;
    const size_t FB_PL   = 256 * 16 * 32;

    float* fout = (float*)d_out;
    const dim3 blk(256);
    const dim3 ggrid(32, 32);
    const size_t WLAYER = (size_t)4 * 1024 * 1024;

    // capture-safe host query: can lstm_pair co-reside 1 block/CU?
    int nb = 0;
    if (hipOccupancyMaxActiveBlocksPerMultiprocessor(&nb, lstm_pair, 256, 0)
        != hipSuccess) nb = 0;

    hipMemsetAsync(ctr, 0, 4 * PAIR_PL * sizeof(int), stream);

    if (nb >= 1) {
        // -------- wavefront path: 2 pre_gemm + 2 lstm_pair --------
        unsigned short* hBhi = (unsigned short*)reg2;
        unsigned short* hBlo = hBhi + 4194304;

        pre_gemm<<<ggrid, blk, 0, stream>>>(x, Wx0, bias, pre, 256);
        for (int p01 = 0; p01 < 2; ++p01) {
            const float* p   = pre;
            const float* whA = Wh + (size_t)(2 * p01) * WLAYER;
            const float* whB = Wh + (size_t)(2 * p01 + 1) * WLAYER;
            const float* wxB = Wx + (size_t)(2 * p01) * WLAYER;      // layer 1 / 3
            const float* bB  = bias + (size_t)(2 * p01 + 1) * 4096;
            float* so = seqA;
            int* cA = ctr + (size_t)(2 * p01) * PAIR_PL;
            int* cB = cA + PAIR_PL;
            int last = (p01 == 1);
            void* args[] = { (void*)&p, (void*)&whA, (void*)&whB, (void*)&wxB,
                             (void*)&bB, (void*)&so, (void*)&hAhi, (void*)&hAlo,
                             (void*)&hBhi, (void*)&hBlo, (void*)&cA, (void*)&cB,
                             (void*)&fout, (void*)&last };
            hipLaunchCooperativeKernel((void*)lstm_pair, dim3(256), blk, args, 0, stream);
            if (p01 == 0)
                pre_gemm<<<ggrid, blk, 0, stream>>>(seqA, Wx + WLAYER,
                                                    bias + 2 * 4096, pre, 1024);
        }
    } else {
        // -------- fallback: EXACT R9 path (proven 6853us) --------
        float* seqB = reg2;
        unsigned short* hhi = hAhi;
        unsigned short* hlo = hAlo;
        for (int l = 0; l < 4; ++l) {
            const float* inp = (l == 0) ? x : ((l & 1) ? seqA : seqB);
            float* outp      = (l & 1) ? seqB : seqA;
            const float* wx  = (l == 0) ? Wx0 : (Wx + (size_t)(l - 1) * WLAYER);
            int K            = (l == 0) ? 256 : 1024;

            pre_gemm<<<ggrid, blk, 0, stream>>>(inp, wx, bias + (size_t)l * 4096, pre, K);

            const float* p = pre;
            const float* wh = Wh + (size_t)l * WLAYER;
            float* so = outp;
            int* pl1 = ctr + (size_t)l * FB_PL;
            int last = (l == 3);
            void* args[] = { (void*)&p, (void*)&wh, (void*)&so, (void*)&hhi,
                             (void*)&hlo, (void*)&pl1, (void*)&fout, (void*)&last };
            hipLaunchCooperativeKernel((void*)lstm_scan, dim3(256), blk, args, 0, stream);
        }
    }
}

// Round 8
// 6879.471 us; speedup vs baseline: 1.0011x; 1.0011x over previous
//
#include <hip/hip_runtime.h>

// B=16, T=256, IN=256, H=1024, L=4, 4 gates -> 4H=4096.
// R11 = R10 wavefront with the pair kernel widened to 512 threads / 8 waves.
// R10 post-mortem: pair step was 10.9us vs R9's 5.5 -- compute phase is
// LATENCY-bound (MfmaUtil 7.3%: pipe idle 93%) at 1 wave/SIMD. 8 waves =
// 2 waves/SIMD co-schedule (m114: max-not-sum) + per-wave serial work halves
// (60 MFMA, 16 h-loads, k-range 128). Weight regs halve to ~144/wave ->
// ~230 VGPR < 256 cap for 2 waves/SIMD (no spill).
// Protocol (flattened per-group counters, dual planes), numerics (3-term
// 5-pass splits), occupancy guard, and the proven R9 fallback: unchanged.
//
// ws (114.1 MB): pre 16,777,216 f | seqA 4,194,304 f
//   | reg2 4,194,304 f  (fallback: seqB | pair: hBhi+hBlo u16 planes)
//   | hAhi/hAlo 4,194,304 u16 each | ctr 528,384 ints

typedef float f32x4 __attribute__((ext_vector_type(4)));
typedef short bf16x8 __attribute__((ext_vector_type(8)));

__device__ __forceinline__ unsigned short f2bf_rn(float x) {
    unsigned int u = __float_as_uint(x);
    u += 0x7FFFu + ((u >> 16) & 1u);          // round-to-nearest-even
    return (unsigned short)(u >> 16);
}
__device__ __forceinline__ float bf2f(unsigned short s) {
    return __uint_as_float(((unsigned int)s) << 16);
}
__device__ __forceinline__ float sigmoidf_(float x) { return 1.0f / (1.0f + __expf(-x)); }
__device__ __forceinline__ float tanhf_(float x) {
    float e = __expf(2.0f * x);
    return 1.0f - 2.0f / (e + 1.0f);
}

#define MFMA16(a, b, c) __builtin_amdgcn_mfma_f32_16x16x32_bf16((a), (b), (c), 0, 0, 0)

// ---------------------------------------------------------------------------
// pre GEMM (proven, unchanged): 128x128 tile, BK=16, fp32.
// ---------------------------------------------------------------------------
__global__ __launch_bounds__(256)
void pre_gemm(const float* __restrict__ A, const float* __restrict__ W,
              const float* __restrict__ bias, float* __restrict__ out, int K)
{
    __shared__ float As[16][132];
    __shared__ float Bs[16][132];

    const int tid = threadIdx.x;
    const int m0 = blockIdx.y << 7;
    const int n0 = blockIdx.x << 7;
    const int g  = n0 >> 10;
    const int jb = n0 & 1023;
    const float* Wg = W + (size_t)g * K * 1024 + jb;

    const int tx = tid & 15;
    const int ty = tid >> 4;
    const int alk = tid & 15;
    const int alm = tid >> 4;
    const int bln = tid & 127;
    const int blkk = tid >> 7;

    float acc[8][8];
#pragma unroll
    for (int i = 0; i < 8; ++i)
#pragma unroll
        for (int j = 0; j < 8; ++j) acc[i][j] = 0.f;

    for (int k0 = 0; k0 < K; k0 += 16) {
        __syncthreads();
#pragma unroll
        for (int r = 0; r < 8; ++r) {
            int m = alm + (r << 4);
            As[alk][m] = A[(size_t)(m0 + m) * K + (k0 + alk)];
        }
#pragma unroll
        for (int r = 0; r < 8; ++r) {
            int kk = blkk + (r << 1);
            Bs[kk][bln] = Wg[(size_t)(k0 + kk) * 1024 + bln];
        }
        __syncthreads();
#pragma unroll
        for (int k = 0; k < 16; ++k) {
            float a[8], bb[8];
            *(f32x4*)&a[0]  = *(const f32x4*)&As[k][ty << 2];
            *(f32x4*)&a[4]  = *(const f32x4*)&As[k][64 + (ty << 2)];
            *(f32x4*)&bb[0] = *(const f32x4*)&Bs[k][tx << 2];
            *(f32x4*)&bb[4] = *(const f32x4*)&Bs[k][64 + (tx << 2)];
#pragma unroll
            for (int i = 0; i < 8; ++i)
#pragma unroll
                for (int j = 0; j < 8; ++j)
                    acc[i][j] = fmaf(a[i], bb[j], acc[i][j]);
        }
    }

    float bj[8];
#pragma unroll
    for (int j = 0; j < 8; ++j) {
        int nloc = (j < 4) ? ((tx << 2) + j) : (64 + (tx << 2) + (j - 4));
        bj[j] = bias[n0 + nloc];
    }
#pragma unroll
    for (int i = 0; i < 8; ++i) {
        int mloc = (i < 4) ? ((ty << 2) + i) : (64 + (ty << 2) + (i - 4));
        int m = m0 + mloc;
        int bidx = m >> 8;
        int tt   = m & 255;
        float* orow = out + ((size_t)((tt << 4) + bidx) << 12) + n0;
#pragma unroll
        for (int j = 0; j < 8; ++j) {
            int nloc = (j < 4) ? ((tx << 2) + j) : (64 + (tx << 2) + (j - 4));
            orow[nloc] = acc[i][j] + bj[j];
        }
    }
}

// ---------------------------------------------------------------------------
// R9 single-layer scan (proven at 6853us total). VERBATIM fallback.
// ---------------------------------------------------------------------------
__global__ __launch_bounds__(256)
void lstm_scan(const float* __restrict__ pre,
               const float* __restrict__ Wh,
               float* __restrict__ seq_out,
               unsigned short* __restrict__ hhi,
               unsigned short* __restrict__ hlo,
               int* __restrict__ ctr_l1,
               float* __restrict__ final_out,
               int is_last)
{
    const int wg   = blockIdx.x;
    const int tid  = threadIdx.x;
    const int wv   = tid >> 6;
    const int lane = tid & 63;
    const int bc   = lane & 15;
    const int quad = lane >> 4;

    __shared__ float red[4][64][4];
    __shared__ float gsh[16][17];

    const int g   = bc >> 2;
    const int col = (wg << 2) + (bc & 3);
    bf16x8 Whi[8], Wmi[8], Wlo[8];
#pragma unroll
    for (int ck = 0; ck < 8; ++ck) {
#pragma unroll
        for (int j = 0; j < 8; ++j) {
            int k = (wv << 8) + (ck << 5) + (quad << 3) + j;
            float w = Wh[((size_t)g << 20) + ((size_t)k << 10) + col];
            unsigned short hi = f2bf_rn(w);
            float r1 = w - bf2f(hi);
            unsigned short mi = f2bf_rn(r1);
            float r2 = r1 - bf2f(mi);
            unsigned short lo = f2bf_rn(r2);
            Whi[ck][j] = (short)hi;
            Wmi[ck][j] = (short)mi;
            Wlo[ck][j] = (short)lo;
        }
    }

    float creg = 0.f;
    int dead = 0;

    for (int t = 0; t < 256; ++t) {
        float pr[4];
        if (wv == 0) {
            const float* pp = pre + ((size_t)t << 16) + ((size_t)(bc >> 2) << 10)
                              + (wg << 2) + (bc & 3);
#pragma unroll
            for (int r = 0; r < 4; ++r)
                pr[r] = pp[(size_t)((quad << 2) + r) << 12];
        }

        if (t > 0 && wv == 0 && !dead) {
            const int* lb = ctr_l1 + (((t - 1) << 4) << 5);
            bool done = (lane >= 16);
            const int gi5 = (lane & 15) << 5;
            int guard = 0;
            for (;;) {
                if (!done)
                    done = __hip_atomic_load(lb + gi5, __ATOMIC_RELAXED,
                                             __HIP_MEMORY_SCOPE_AGENT) >= 16;
                if (__all(done)) break;
                __builtin_amdgcn_s_sleep(1);
                if (++guard > (1 << 15)) { dead = 1; break; }
            }
        }
        __syncthreads();
        asm volatile("" ::: "memory");

        f32x4 a00 = {0.f, 0.f, 0.f, 0.f};
        f32x4 a01 = a00, a10 = a00, a11 = a00;
        if (t > 0) {
            const size_t pb = ((size_t)(t - 1) << 14) + ((size_t)bc << 10) + (wv << 8);
            const unsigned short* ph = hhi + pb;
            const unsigned short* pl = hlo + pb;
            bf16x8 ahi[8], alo[8];
#pragma unroll
            for (int ck = 0; ck < 8; ++ck) {
                ahi[ck] = *(const bf16x8*)(ph + (ck << 5) + (quad << 3));
                alo[ck] = *(const bf16x8*)(pl + (ck << 5) + (quad << 3));
            }
#pragma unroll
            for (int ck = 0; ck < 8; ++ck) {
                if (ck & 1) {
                    a10 = MFMA16(ahi[ck], Whi[ck], a10);
                    a11 = MFMA16(ahi[ck], Wmi[ck], a11);
                    a10 = MFMA16(ahi[ck], Wlo[ck], a10);
                    a11 = MFMA16(alo[ck], Whi[ck], a11);
                    a10 = MFMA16(alo[ck], Wmi[ck], a10);
                } else {
                    a00 = MFMA16(ahi[ck], Whi[ck], a00);
                    a01 = MFMA16(ahi[ck], Wmi[ck], a01);
                    a00 = MFMA16(ahi[ck], Wlo[ck], a00);
                    a01 = MFMA16(alo[ck], Whi[ck], a01);
                    a00 = MFMA16(alo[ck], Wmi[ck], a00);
                }
            }
        }
        f32x4 acc = (a00 + a01) + (a10 + a11);
        *(f32x4*)&red[wv][lane][0] = acc;
        __syncthreads();

        if (wv == 0) {
            f32x4 s0 = *(const f32x4*)&red[0][lane][0];
            f32x4 s1 = *(const f32x4*)&red[1][lane][0];
            f32x4 s2 = *(const f32x4*)&red[2][lane][0];
            f32x4 s3 = *(const f32x4*)&red[3][lane][0];
            f32x4 s = (s0 + s1) + (s2 + s3);
#pragma unroll
            for (int r = 0; r < 4; ++r)
                gsh[(quad << 2) + r][bc] = s[r] + pr[r];

            const int b2 = lane >> 2, jl2 = lane & 3;
            float fg = sigmoidf_(gsh[b2][jl2]);
            float ig = sigmoidf_(gsh[b2][4 + jl2]);
            float pg = tanhf_(gsh[b2][8 + jl2]);
            float og = sigmoidf_(gsh[b2][12 + jl2]);
            creg = fg * creg + ig * pg;
            float h = tanhf_(creg) * og;

            const int j = (wg << 2) + jl2;
            unsigned short hh = f2bf_rn(h);
            unsigned short hl = f2bf_rn(h - bf2f(hh));
            size_t pidx = ((size_t)t << 14) + ((size_t)b2 << 10) + j;
            __hip_atomic_store(&hhi[pidx], hh, __ATOMIC_RELAXED, __HIP_MEMORY_SCOPE_AGENT);
            __hip_atomic_store(&hlo[pidx], hl, __ATOMIC_RELAXED, __HIP_MEMORY_SCOPE_AGENT);
            if (is_last && t == 255) final_out[((size_t)b2 << 10) + j] = h;

            __builtin_amdgcn_s_waitcnt(0);
            if (lane == 0)
                __hip_atomic_fetch_add(&ctr_l1[((t << 4) + (wg >> 4)) << 5], 1,
                                       __ATOMIC_RELAXED,
                                       __HIP_MEMORY_SCOPE_AGENT);

            if (!is_last)
                seq_out[((size_t)((b2 << 8) + t) << 10) + j] = h;
        }
    }
}

// ---------------------------------------------------------------------------
// Layer-pair wavefront, 512 threads / 8 waves. Wave wv owns k-range
// [wv*128, +128) = 4 ck-blocks: 60 MFMA + 16 h-loads per wave per step
// (half of R10's 4-wave version); 2 waves/SIMD co-schedule hides latency.
// Step s: [A-scan t=s | B-pre t'=s-1 | B-scan t1=s-2], 2 barriers.
// wave0: poll + A gates -> hA -> drain -> ctrA. wave1: B gates -> hB ->
// drain -> ctrB (seq/final off-drain). wave2: B-pre ring. waves 3-7: MFMA only.
// ---------------------------------------------------------------------------
__global__ __launch_bounds__(512)
void lstm_pair(const float* __restrict__ preA,   // [256][16][4096]
               const float* __restrict__ WhA,    // [4][1024][1024]
               const float* __restrict__ WhB,    // [4][1024][1024]
               const float* __restrict__ WxB,    // [4][1024][1024]
               const float* __restrict__ biasB,  // [4][1024]
               float* __restrict__ seq_out,      // [16][256][1024] (!is_last)
               unsigned short* __restrict__ hAhi, unsigned short* __restrict__ hAlo,
               unsigned short* __restrict__ hBhi, unsigned short* __restrict__ hBlo,
               int* __restrict__ ctrA,           // [258 s][16 grp] stride-32
               int* __restrict__ ctrB,           // [258 s][16 grp] stride-32
               float* __restrict__ final_out,    // [16][1024]
               int is_last)
{
    const int wg   = blockIdx.x;
    const int tid  = threadIdx.x;
    const int wv   = tid >> 6;        // 8 waves; wave owns k [wv*128, +128)
    const int lane = tid & 63;
    const int bc   = lane & 15;
    const int quad = lane >> 4;

    __shared__ float red[3][8][64][4]; // [A | B-pre | B-scan] 8-way reductions
    __shared__ float gsh[2][16][17];   // gate exchange [A/B][b][g*4+jl]
    __shared__ float ring[2][16][17];  // B-pre ring: preB[t'] in slot t'&1

    const int g   = bc >> 2;
    const int col = (wg << 2) + (bc & 3);

    // one-time: 3-term bf16 splits, 4 ck-blocks per wave (144 weight VGPRs)
    bf16x8 WAh[4], WAm[4], WAl[4];
    bf16x8 WBh[4], WBm[4], WBl[4];
    bf16x8 WXh[4], WXm[4], WXl[4];
#pragma unroll
    for (int ck = 0; ck < 4; ++ck) {
#pragma unroll
        for (int j = 0; j < 8; ++j) {
            const int k = (wv << 7) + (ck << 5) + (quad << 3) + j;
            const size_t widx = ((size_t)g << 20) + ((size_t)k << 10) + col;
            {
                float w = WhA[widx];
                unsigned short hi = f2bf_rn(w); float r1 = w - bf2f(hi);
                unsigned short mi = f2bf_rn(r1); float r2 = r1 - bf2f(mi);
                WAh[ck][j] = (short)hi; WAm[ck][j] = (short)mi;
                WAl[ck][j] = (short)f2bf_rn(r2);
            }
            {
                float w = WhB[widx];
                unsigned short hi = f2bf_rn(w); float r1 = w - bf2f(hi);
                unsigned short mi = f2bf_rn(r1); float r2 = r1 - bf2f(mi);
                WBh[ck][j] = (short)hi; WBm[ck][j] = (short)mi;
                WBl[ck][j] = (short)f2bf_rn(r2);
            }
            {
                float w = WxB[widx];
                unsigned short hi = f2bf_rn(w); float r1 = w - bf2f(hi);
                unsigned short mi = f2bf_rn(r1); float r2 = r1 - bf2f(mi);
                WXh[ck][j] = (short)hi; WXm[ck][j] = (short)mi;
                WXl[ck][j] = (short)f2bf_rn(r2);
            }
        }
    }
    const float biasv = biasB[((size_t)g << 10) + col];

    float creg = 0.f;   // wave0 lanes: layer-A cell; wave1 lanes: layer-B cell
    int dead = 0;

    for (int s = 0; s < 258; ++s) {
        float pr[4];
        if (wv == 0 && s < 256) {
            const float* pp = preA + ((size_t)s << 16) + ((size_t)g << 10) + col;
#pragma unroll
            for (int r = 0; r < 4; ++r)
                pr[r] = pp[(size_t)((quad << 2) + r) << 12];
        }

        if (s > 0 && wv == 0 && !dead) {
            // lanes 0-15: ctrA[s-1][grp] (exists for s<=256);
            // lanes 16-31: ctrB[s-1][grp] (exists for s>=3); others done.
            bool done;
            const int gi = lane & 15;
            const int* wp;
            if (lane < 16)      { done = (s > 256); wp = ctrA + (((s - 1) << 4) + gi) * 32; }
            else if (lane < 32) { done = (s < 3);   wp = ctrB + (((s - 1) << 4) + gi) * 32; }
            else                { done = true;      wp = ctrA; }
            int guard = 0;
            for (;;) {
                if (!done)
                    done = __hip_atomic_load(wp, __ATOMIC_RELAXED,
                                             __HIP_MEMORY_SCOPE_AGENT) >= 16;
                if (__all(done)) break;
                __builtin_amdgcn_s_sleep(1);
                if (++guard > (1 << 14)) { dead = 1; break; }  // bug -> fast wrong answer
            }
        }
        __syncthreads();
        asm volatile("" ::: "memory");

        f32x4 aA0 = {0.f, 0.f, 0.f, 0.f}, aA1 = aA0;
        f32x4 aP0 = aA0, aP1 = aA0;
        f32x4 aB0 = aA0, aB1 = aA0;

        if (s >= 1 && s <= 256) {            // consume hA(s-1): A-scan + B-pre
            const size_t pb = ((size_t)(s - 1) << 14) + ((size_t)bc << 10) + (wv << 7);
            const unsigned short* ph = hAhi + pb;
            const unsigned short* pl = hAlo + pb;
#pragma unroll
            for (int ck = 0; ck < 4; ++ck) {   // streamed frags
                bf16x8 ah = *(const bf16x8*)(ph + (ck << 5) + (quad << 3));
                bf16x8 al = *(const bf16x8*)(pl + (ck << 5) + (quad << 3));
                if (ck & 1) {
                    aA1 = MFMA16(ah, WAh[ck], aA1);
                    aA1 = MFMA16(ah, WAm[ck], aA1);
                    aA1 = MFMA16(ah, WAl[ck], aA1);
                    aA1 = MFMA16(al, WAh[ck], aA1);
                    aA1 = MFMA16(al, WAm[ck], aA1);
                    aP1 = MFMA16(ah, WXh[ck], aP1);
                    aP1 = MFMA16(ah, WXm[ck], aP1);
                    aP1 = MFMA16(ah, WXl[ck], aP1);
                    aP1 = MFMA16(al, WXh[ck], aP1);
                    aP1 = MFMA16(al, WXm[ck], aP1);
                } else {
                    aA0 = MFMA16(ah, WAh[ck], aA0);
                    aA0 = MFMA16(ah, WAm[ck], aA0);
                    aA0 = MFMA16(ah, WAl[ck], aA0);
                    aA0 = MFMA16(al, WAh[ck], aA0);
                    aA0 = MFMA16(al, WAm[ck], aA0);
                    aP0 = MFMA16(ah, WXh[ck], aP0);
                    aP0 = MFMA16(ah, WXm[ck], aP0);
                    aP0 = MFMA16(ah, WXl[ck], aP0);
                    aP0 = MFMA16(al, WXh[ck], aP0);
                    aP0 = MFMA16(al, WXm[ck], aP0);
                }
            }
        }
        if (s >= 3) {                        // consume hB(s-3): B-scan
            const size_t pb = ((size_t)(s - 3) << 14) + ((size_t)bc << 10) + (wv << 7);
            const unsigned short* ph = hBhi + pb;
            const unsigned short* pl = hBlo + pb;
#pragma unroll
            for (int ck = 0; ck < 4; ++ck) {
                bf16x8 bh = *(const bf16x8*)(ph + (ck << 5) + (quad << 3));
                bf16x8 bl = *(const bf16x8*)(pl + (ck << 5) + (quad << 3));
                if (ck & 1) {
                    aB1 = MFMA16(bh, WBh[ck], aB1);
                    aB1 = MFMA16(bh, WBm[ck], aB1);
                    aB1 = MFMA16(bh, WBl[ck], aB1);
                    aB1 = MFMA16(bl, WBh[ck], aB1);
                    aB1 = MFMA16(bl, WBm[ck], aB1);
                } else {
                    aB0 = MFMA16(bh, WBh[ck], aB0);
                    aB0 = MFMA16(bh, WBm[ck], aB0);
                    aB0 = MFMA16(bh, WBl[ck], aB0);
                    aB0 = MFMA16(bl, WBh[ck], aB0);
                    aB0 = MFMA16(bl, WBm[ck], aB0);
                }
            }
        }

        *(f32x4*)&red[0][wv][lane][0] = aA0 + aA1;
        *(f32x4*)&red[1][wv][lane][0] = aP0 + aP1;
        *(f32x4*)&red[2][wv][lane][0] = aB0 + aB1;
        __syncthreads();

        if (wv == 0) {
            if (s <= 255) {                                  // layer A, t = s
                f32x4 sm = {0.f, 0.f, 0.f, 0.f};
#pragma unroll
                for (int w = 0; w < 8; ++w)
                    sm += *(const f32x4*)&red[0][w][lane][0];
#pragma unroll
                for (int r = 0; r < 4; ++r)
                    gsh[0][(quad << 2) + r][bc] = sm[r] + pr[r];

                const int b2 = lane >> 2, jl2 = lane & 3;
                float fg = sigmoidf_(gsh[0][b2][jl2]);
                float ig = sigmoidf_(gsh[0][b2][4 + jl2]);
                float pg = tanhf_(gsh[0][b2][8 + jl2]);
                float og = sigmoidf_(gsh[0][b2][12 + jl2]);
                creg = fg * creg + ig * pg;
                float h = tanhf_(creg) * og;
                const int j = (wg << 2) + jl2;
                unsigned short hh = f2bf_rn(h);
                unsigned short hl = f2bf_rn(h - bf2f(hh));
                size_t pidx = ((size_t)s << 14) + ((size_t)b2 << 10) + j;
                __hip_atomic_store(&hAhi[pidx], hh, __ATOMIC_RELAXED, __HIP_MEMORY_SCOPE_AGENT);
                __hip_atomic_store(&hAlo[pidx], hl, __ATOMIC_RELAXED, __HIP_MEMORY_SCOPE_AGENT);
                __builtin_amdgcn_s_waitcnt(0);
                if (lane == 0)
                    __hip_atomic_fetch_add(&ctrA[((s << 4) + (wg >> 4)) << 5], 1,
                                           __ATOMIC_RELAXED,
                                           __HIP_MEMORY_SCOPE_AGENT);
            }
        } else if (wv == 1) {
            if (s >= 2) {                                    // layer B, t1 = s-2
                const int t1 = s - 2;
                f32x4 sm = {0.f, 0.f, 0.f, 0.f};
#pragma unroll
                for (int w = 0; w < 8; ++w)
                    sm += *(const f32x4*)&red[2][w][lane][0];
#pragma unroll
                for (int r = 0; r < 4; ++r)
                    gsh[1][(quad << 2) + r][bc] =
                        sm[r] + ring[t1 & 1][(quad << 2) + r][bc];

                const int b2 = lane >> 2, jl2 = lane & 3;
                float fg = sigmoidf_(gsh[1][b2][jl2]);
                float ig = sigmoidf_(gsh[1][b2][4 + jl2]);
                float pg = tanhf_(gsh[1][b2][8 + jl2]);
                float og = sigmoidf_(gsh[1][b2][12 + jl2]);
                creg = fg * creg + ig * pg;
                float h = tanhf_(creg) * og;
                const int j = (wg << 2) + jl2;
                unsigned short hh = f2bf_rn(h);
                unsigned short hl = f2bf_rn(h - bf2f(hh));
                size_t pidx = ((size_t)t1 << 14) + ((size_t)b2 << 10) + j;
                __hip_atomic_store(&hBhi[pidx], hh, __ATOMIC_RELAXED, __HIP_MEMORY_SCOPE_AGENT);
                __hip_atomic_store(&hBlo[pidx], hl, __ATOMIC_RELAXED, __HIP_MEMORY_SCOPE_AGENT);
                __builtin_amdgcn_s_waitcnt(0);
                if (lane == 0)
                    __hip_atomic_fetch_add(&ctrB[((s << 4) + (wg >> 4)) << 5], 1,
                                           __ATOMIC_RELAXED,
                                           __HIP_MEMORY_SCOPE_AGENT);
                if (!is_last)
                    seq_out[((size_t)((b2 << 8) + t1) << 10) + j] = h;   // next dispatch
                if (is_last && t1 == 255)
                    final_out[((size_t)b2 << 10) + j] = h;
            }
        } else if (wv == 2) {
            if (s >= 1 && s <= 256) {                        // B-pre for t' = s-1
                f32x4 qm = {0.f, 0.f, 0.f, 0.f};
#pragma unroll
                for (int w = 0; w < 8; ++w)
                    qm += *(const f32x4*)&red[1][w][lane][0];
#pragma unroll
                for (int r = 0; r < 4; ++r)
                    ring[(s - 1) & 1][(quad << 2) + r][bc] = qm[r] + biasv;
            }
        }
    }
}

// ---------------------------------------------------------------------------
extern "C" void kernel_launch(void* const* d_in, const int* in_sizes, int n_in,
                              void* d_out, int out_size, void* d_ws, size_t ws_size,
                              hipStream_t stream)
{
    (void)in_sizes; (void)n_in; (void)out_size; (void)ws_size;

    const float* x    = (const float*)d_in[0];   // [16][256][256]
    const float* Wh   = (const float*)d_in[1];   // [4][4][1024][1024]
    const float* Wx0  = (const float*)d_in[2];   // [4][256][1024]
    const float* Wx   = (const float*)d_in[3];   // [3][4][1024][1024]
    const float* bias = (const float*)d_in[4];   // [4][4][1024]

    float* pre  = (float*)d_ws;                    // 16,777,216 f
    float* seqA = pre + 16777216;                  // 4,194,304 f
    float* reg2 = seqA + 4194304;                  // 4,194,304 f (aliased)
    unsigned short* hAhi = (unsigned short*)(reg2 + 4194304);  // 4,194,304 u16
    unsigned short* hAlo = hAhi + 4194304;                     // 4,194,304 u16
    int* ctr = (int*)(hAlo + 4194304);
    const size_t PAIR_PL = 258 * 16 * 32;
    const size_t FB_PL   = 256 * 16 * 32;

    float* fout = (float*)d_out;
    const dim3 blk(256);
    const dim3 blkP(512);
    const dim3 ggrid(32, 32);
    const size_t WLAYER = (size_t)4 * 1024 * 1024;

    // capture-safe host query: can the 512-thread pair kernel co-reside?
    int nb = 0;
    if (hipOccupancyMaxActiveBlocksPerMultiprocessor(&nb, lstm_pair, 512, 0)
        != hipSuccess) nb = 0;

    hipMemsetAsync(ctr, 0, 4 * PAIR_PL * sizeof(int), stream);

    if (nb >= 1) {
        // -------- wavefront path: 2 pre_gemm + 2 lstm_pair (512 thr) --------
        unsigned short* hBhi = (unsigned short*)reg2;
        unsigned short* hBlo = hBhi + 4194304;

        pre_gemm<<<ggrid, blk, 0, stream>>>(x, Wx0, bias, pre, 256);
        for (int p01 = 0; p01 < 2; ++p01) {
            const float* p   = pre;
            const float* whA = Wh + (size_t)(2 * p01) * WLAYER;
            const float* whB = Wh + (size_t)(2 * p01 + 1) * WLAYER;
            const float* wxB = Wx + (size_t)(2 * p01) * WLAYER;      // layer 1 / 3
            const float* bB  = bias + (size_t)(2 * p01 + 1) * 4096;
            float* so = seqA;
            int* cA = ctr + (size_t)(2 * p01) * PAIR_PL;
            int* cB = cA + PAIR_PL;
            int last = (p01 == 1);
            void* args[] = { (void*)&p, (void*)&whA, (void*)&whB, (void*)&wxB,
                             (void*)&bB, (void*)&so, (void*)&hAhi, (void*)&hAlo,
                             (void*)&hBhi, (void*)&hBlo, (void*)&cA, (void*)&cB,
                             (void*)&fout, (void*)&last };
            hipLaunchCooperativeKernel((void*)lstm_pair, dim3(256), blkP, args, 0, stream);
            if (p01 == 0)
                pre_gemm<<<ggrid, blk, 0, stream>>>(seqA, Wx + WLAYER,
                                                    bias + 2 * 4096, pre, 1024);
        }
    } else {
        // -------- fallback: EXACT R9 path (proven 6853us) --------
        float* seqB = reg2;
        unsigned short* hhi = hAhi;
        unsigned short* hlo = hAlo;
        for (int l = 0; l < 4; ++l) {
            const float* inp = (l == 0) ? x : ((l & 1) ? seqA : seqB);
            float* outp      = (l & 1) ? seqB : seqA;
            const float* wx  = (l == 0) ? Wx0 : (Wx + (size_t)(l - 1) * WLAYER);
            int K            = (l == 0) ? 256 : 1024;

            pre_gemm<<<ggrid, blk, 0, stream>>>(inp, wx, bias + (size_t)l * 4096, pre, K);

            const float* p = pre;
            const float* wh = Wh + (size_t)l * WLAYER;
            float* so = outp;
            int* pl1 = ctr + (size_t)l * FB_PL;
            int last = (l == 3);
            void* args[] = { (void*)&p, (void*)&wh, (void*)&so, (void*)&hhi,
                             (void*)&hlo, (void*)&pl1, (void*)&fout, (void*)&last };
            hipLaunchCooperativeKernel((void*)lstm_scan, dim3(256), blk, args, 0, stream);
        }
    }
}

// Round 10
// 6827.777 us; speedup vs baseline: 1.0086x; 1.0076x over previous
//
#include <hip/hip_runtime.h>

// B=16, T=256, IN=256, H=1024, L=4, 4 gates -> 4H=4096.
// R13 = R12 fused incremental next-layer pre + R10-style occupancy guard +
// verbatim-R9 fallback.
// Empirical launch rule (5/5 rounds): big cooperative kernels launched WITHOUT
// the hipOccupancyMaxActiveBlocksPerMultiprocessor guard silently never run
// (output stays memset-zero: R4/5/7/8/12); guarded ones always ran (R10/R11).
// Fused design (analyzed in R12): scan(l) step s also computes
// h_l(s-1) @ Wx(l+1) (3-term/5-pass bf16) AFTER barrier #2, overlapping the
// finish/drain/poll window; wave1 reduces the previous double-buffered redP
// plane into pre[s-2] IN PLACE (own 16 columns; reader done 2 barriers ago;
// cross-wg columns disjoint). Kills pre_gemm #2..4 and all seq stores.
// Register trim vs R12: P-phase RELOADS h frags per-ck (L1/L2-hot) instead of
// keeping ahi/alo live across the finish (-64 regs peak liveness).
//
// ws (R9 layout, ~114 MB): pre 16,777,216 f | seqA/seqB 4,194,304 f each
//   | hhi/hlo 4,194,304 u16 each | ctr 4 x 256 x 16 x 32 ints

typedef float f32x4 __attribute__((ext_vector_type(4)));
typedef short bf16x8 __attribute__((ext_vector_type(8)));

__device__ __forceinline__ unsigned short f2bf_rn(float x) {
    unsigned int u = __float_as_uint(x);
    u += 0x7FFFu + ((u >> 16) & 1u);          // round-to-nearest-even
    return (unsigned short)(u >> 16);
}
__device__ __forceinline__ float bf2f(unsigned short s) {
    return __uint_as_float(((unsigned int)s) << 16);
}
__device__ __forceinline__ float sigmoidf_(float x) { return 1.0f / (1.0f + __expf(-x)); }
__device__ __forceinline__ float tanhf_(float x) {
    float e = __expf(2.0f * x);
    return 1.0f - 2.0f / (e + 1.0f);
}

#define MFMA16(a, b, c) __builtin_amdgcn_mfma_f32_16x16x32_bf16((a), (b), (c), 0, 0, 0)

// ---------------------------------------------------------------------------
// pre GEMM (proven, unchanged): 128x128 tile, BK=16, fp32.
// ---------------------------------------------------------------------------
__global__ __launch_bounds__(256)
void pre_gemm(const float* __restrict__ A, const float* __restrict__ W,
              const float* __restrict__ bias, float* __restrict__ out, int K)
{
    __shared__ float As[16][132];
    __shared__ float Bs[16][132];

    const int tid = threadIdx.x;
    const int m0 = blockIdx.y << 7;
    const int n0 = blockIdx.x << 7;
    const int g  = n0 >> 10;
    const int jb = n0 & 1023;
    const float* Wg = W + (size_t)g * K * 1024 + jb;

    const int tx = tid & 15;
    const int ty = tid >> 4;
    const int alk = tid & 15;
    const int alm = tid >> 4;
    const int bln = tid & 127;
    const int blkk = tid >> 7;

    float acc[8][8];
#pragma unroll
    for (int i = 0; i < 8; ++i)
#pragma unroll
        for (int j = 0; j < 8; ++j) acc[i][j] = 0.f;

    for (int k0 = 0; k0 < K; k0 += 16) {
        __syncthreads();
#pragma unroll
        for (int r = 0; r < 8; ++r) {
            int m = alm + (r << 4);
            As[alk][m] = A[(size_t)(m0 + m) * K + (k0 + alk)];
        }
#pragma unroll
        for (int r = 0; r < 8; ++r) {
            int kk = blkk + (r << 1);
            Bs[kk][bln] = Wg[(size_t)(k0 + kk) * 1024 + bln];
        }
        __syncthreads();
#pragma unroll
        for (int k = 0; k < 16; ++k) {
            float a[8], bb[8];
            *(f32x4*)&a[0]  = *(const f32x4*)&As[k][ty << 2];
            *(f32x4*)&a[4]  = *(const f32x4*)&As[k][64 + (ty << 2)];
            *(f32x4*)&bb[0] = *(const f32x4*)&Bs[k][tx << 2];
            *(f32x4*)&bb[4] = *(const f32x4*)&Bs[k][64 + (tx << 2)];
#pragma unroll
            for (int i = 0; i < 8; ++i)
#pragma unroll
                for (int j = 0; j < 8; ++j)
                    acc[i][j] = fmaf(a[i], bb[j], acc[i][j]);
        }
    }

    float bj[8];
#pragma unroll
    for (int j = 0; j < 8; ++j) {
        int nloc = (j < 4) ? ((tx << 2) + j) : (64 + (tx << 2) + (j - 4));
        bj[j] = bias[n0 + nloc];
    }
#pragma unroll
    for (int i = 0; i < 8; ++i) {
        int mloc = (i < 4) ? ((ty << 2) + i) : (64 + (ty << 2) + (i - 4));
        int m = m0 + mloc;
        int bidx = m >> 8;
        int tt   = m & 255;
        float* orow = out + ((size_t)((tt << 4) + bidx) << 12) + n0;
#pragma unroll
        for (int j = 0; j < 8; ++j) {
            int nloc = (j < 4) ? ((tx << 2) + j) : (64 + (tx << 2) + (j - 4));
            orow[nloc] = acc[i][j] + bj[j];
        }
    }
}

// ---------------------------------------------------------------------------
// R9 single-layer scan (proven at 6853us total). VERBATIM fallback.
// ---------------------------------------------------------------------------
__global__ __launch_bounds__(256)
void lstm_scan(const float* __restrict__ pre,
               const float* __restrict__ Wh,
               float* __restrict__ seq_out,
               unsigned short* __restrict__ hhi,
               unsigned short* __restrict__ hlo,
               int* __restrict__ ctr_l1,
               float* __restrict__ final_out,
               int is_last)
{
    const int wg   = blockIdx.x;
    const int tid  = threadIdx.x;
    const int wv   = tid >> 6;
    const int lane = tid & 63;
    const int bc   = lane & 15;
    const int quad = lane >> 4;

    __shared__ float red[4][64][4];
    __shared__ float gsh[16][17];

    const int g   = bc >> 2;
    const int col = (wg << 2) + (bc & 3);
    bf16x8 Whi[8], Wmi[8], Wlo[8];
#pragma unroll
    for (int ck = 0; ck < 8; ++ck) {
#pragma unroll
        for (int j = 0; j < 8; ++j) {
            int k = (wv << 8) + (ck << 5) + (quad << 3) + j;
            float w = Wh[((size_t)g << 20) + ((size_t)k << 10) + col];
            unsigned short hi = f2bf_rn(w);
            float r1 = w - bf2f(hi);
            unsigned short mi = f2bf_rn(r1);
            float r2 = r1 - bf2f(mi);
            unsigned short lo = f2bf_rn(r2);
            Whi[ck][j] = (short)hi;
            Wmi[ck][j] = (short)mi;
            Wlo[ck][j] = (short)lo;
        }
    }

    float creg = 0.f;
    int dead = 0;

    for (int t = 0; t < 256; ++t) {
        float pr[4];
        if (wv == 0) {
            const float* pp = pre + ((size_t)t << 16) + ((size_t)(bc >> 2) << 10)
                              + (wg << 2) + (bc & 3);
#pragma unroll
            for (int r = 0; r < 4; ++r)
                pr[r] = pp[(size_t)((quad << 2) + r) << 12];
        }

        if (t > 0 && wv == 0 && !dead) {
            const int* lb = ctr_l1 + (((t - 1) << 4) << 5);
            bool done = (lane >= 16);
            const int gi5 = (lane & 15) << 5;
            int guard = 0;
            for (;;) {
                if (!done)
                    done = __hip_atomic_load(lb + gi5, __ATOMIC_RELAXED,
                                             __HIP_MEMORY_SCOPE_AGENT) >= 16;
                if (__all(done)) break;
                __builtin_amdgcn_s_sleep(1);
                if (++guard > (1 << 15)) { dead = 1; break; }
            }
        }
        __syncthreads();
        asm volatile("" ::: "memory");

        f32x4 a00 = {0.f, 0.f, 0.f, 0.f};
        f32x4 a01 = a00, a10 = a00, a11 = a00;
        if (t > 0) {
            const size_t pb = ((size_t)(t - 1) << 14) + ((size_t)bc << 10) + (wv << 8);
            const unsigned short* ph = hhi + pb;
            const unsigned short* pl = hlo + pb;
            bf16x8 ahi[8], alo[8];
#pragma unroll
            for (int ck = 0; ck < 8; ++ck) {
                ahi[ck] = *(const bf16x8*)(ph + (ck << 5) + (quad << 3));
                alo[ck] = *(const bf16x8*)(pl + (ck << 5) + (quad << 3));
            }
#pragma unroll
            for (int ck = 0; ck < 8; ++ck) {
                if (ck & 1) {
                    a10 = MFMA16(ahi[ck], Whi[ck], a10);
                    a11 = MFMA16(ahi[ck], Wmi[ck], a11);
                    a10 = MFMA16(ahi[ck], Wlo[ck], a10);
                    a11 = MFMA16(alo[ck], Whi[ck], a11);
                    a10 = MFMA16(alo[ck], Wmi[ck], a10);
                } else {
                    a00 = MFMA16(ahi[ck], Whi[ck], a00);
                    a01 = MFMA16(ahi[ck], Wmi[ck], a01);
                    a00 = MFMA16(ahi[ck], Wlo[ck], a00);
                    a01 = MFMA16(alo[ck], Whi[ck], a01);
                    a00 = MFMA16(alo[ck], Wmi[ck], a00);
                }
            }
        }
        f32x4 acc = (a00 + a01) + (a10 + a11);
        *(f32x4*)&red[wv][lane][0] = acc;
        __syncthreads();

        if (wv == 0) {
            f32x4 s0 = *(const f32x4*)&red[0][lane][0];
            f32x4 s1 = *(const f32x4*)&red[1][lane][0];
            f32x4 s2 = *(const f32x4*)&red[2][lane][0];
            f32x4 s3 = *(const f32x4*)&red[3][lane][0];
            f32x4 s = (s0 + s1) + (s2 + s3);
#pragma unroll
            for (int r = 0; r < 4; ++r)
                gsh[(quad << 2) + r][bc] = s[r] + pr[r];

            const int b2 = lane >> 2, jl2 = lane & 3;
            float fg = sigmoidf_(gsh[b2][jl2]);
            float ig = sigmoidf_(gsh[b2][4 + jl2]);
            float pg = tanhf_(gsh[b2][8 + jl2]);
            float og = sigmoidf_(gsh[b2][12 + jl2]);
            creg = fg * creg + ig * pg;
            float h = tanhf_(creg) * og;

            const int j = (wg << 2) + jl2;
            unsigned short hh = f2bf_rn(h);
            unsigned short hl = f2bf_rn(h - bf2f(hh));
            size_t pidx = ((size_t)t << 14) + ((size_t)b2 << 10) + j;
            __hip_atomic_store(&hhi[pidx], hh, __ATOMIC_RELAXED, __HIP_MEMORY_SCOPE_AGENT);
            __hip_atomic_store(&hlo[pidx], hl, __ATOMIC_RELAXED, __HIP_MEMORY_SCOPE_AGENT);
            if (is_last && t == 255) final_out[((size_t)b2 << 10) + j] = h;

            __builtin_amdgcn_s_waitcnt(0);
            if (lane == 0)
                __hip_atomic_fetch_add(&ctr_l1[((t << 4) + (wg >> 4)) << 5], 1,
                                       __ATOMIC_RELAXED,
                                       __HIP_MEMORY_SCOPE_AGENT);

            if (!is_last)
                seq_out[((size_t)((b2 << 8) + t) << 10) + j] = h;
        }
    }
}

// ---------------------------------------------------------------------------
// Fused scan: R9 step + off-critical next-layer pre (see header comment).
// ---------------------------------------------------------------------------
__global__ __launch_bounds__(256)
void lstm_scan_fused(float* pre,                  // [256][16][4096] in/out
               const float* __restrict__ Wh,     // this layer [4][1024][1024]
               const float* __restrict__ WxN,    // NEXT layer Wx [4][1024][1024]
               const float* __restrict__ biasN,  // NEXT layer bias [4][1024]
               unsigned short* __restrict__ hhi, // [T][16][1024] bf16 hi plane
               unsigned short* __restrict__ hlo, // [T][16][1024] bf16 lo plane
               int* __restrict__ ctr_l1,         // [256 t][16 grp] stride-32
               float* __restrict__ final_out,    // [16][1024]
               int is_last, int has_next)
{
    const int wg   = blockIdx.x;
    const int tid  = threadIdx.x;
    const int wv   = tid >> 6;        // wave 0..3 owns k-range [wv*256, +256)
    const int lane = tid & 63;
    const int bc   = lane & 15;
    const int quad = lane >> 4;

    __shared__ float red[4][64][4];      // A-scan cross-wave reduction
    __shared__ float redP[2][4][64][4];  // next-layer-pre, double-buffered
    __shared__ float gsh[16][17];

    const int g   = bc >> 2;
    const int col = (wg << 2) + (bc & 3);
    bf16x8 Whi[8], Wmi[8], Wlo[8];
#pragma unroll
    for (int ck = 0; ck < 8; ++ck) {
#pragma unroll
        for (int j = 0; j < 8; ++j) {
            int k = (wv << 8) + (ck << 5) + (quad << 3) + j;
            float w = Wh[((size_t)g << 20) + ((size_t)k << 10) + col];
            unsigned short hi = f2bf_rn(w);
            float r1 = w - bf2f(hi);
            unsigned short mi = f2bf_rn(r1);
            float r2 = r1 - bf2f(mi);
            unsigned short lo = f2bf_rn(r2);
            Whi[ck][j] = (short)hi;
            Wmi[ck][j] = (short)mi;
            Wlo[ck][j] = (short)lo;
        }
    }
    bf16x8 WXh[8], WXm[8], WXl[8];
    if (has_next) {
#pragma unroll
        for (int ck = 0; ck < 8; ++ck) {
#pragma unroll
            for (int j = 0; j < 8; ++j) {
                int k = (wv << 8) + (ck << 5) + (quad << 3) + j;
                float w = WxN[((size_t)g << 20) + ((size_t)k << 10) + col];
                unsigned short hi = f2bf_rn(w);
                float r1 = w - bf2f(hi);
                unsigned short mi = f2bf_rn(r1);
                float r2 = r1 - bf2f(mi);
                unsigned short lo = f2bf_rn(r2);
                WXh[ck][j] = (short)hi;
                WXm[ck][j] = (short)mi;
                WXl[ck][j] = (short)lo;
            }
        }
    }
    const float biasvN = biasN[((size_t)g << 10) + col];

    float creg = 0.f;
    int dead = 0;
    const int smax = has_next ? 258 : 256;

    for (int s = 0; s < smax; ++s) {
        float pr[4];
        if (wv == 0 && s < 256) {
            const float* pp = pre + ((size_t)s << 16) + ((size_t)g << 10) + col;
#pragma unroll
            for (int r = 0; r < 4; ++r)
                pr[r] = pp[(size_t)((quad << 2) + r) << 12];
        }

        if (s >= 1 && s <= 256 && wv == 0 && !dead) {
            const int* lb = ctr_l1 + (((s - 1) << 4) << 5);
            bool done = (lane >= 16);
            const int gi5 = (lane & 15) << 5;
            int guard = 0;
            for (;;) {
                if (!done)
                    done = __hip_atomic_load(lb + gi5, __ATOMIC_RELAXED,
                                             __HIP_MEMORY_SCOPE_AGENT) >= 16;
                if (__all(done)) break;
                __builtin_amdgcn_s_sleep(1);
                if (++guard > (1 << 15)) { dead = 1; break; }
            }
        }
        __syncthreads();
        asm volatile("" ::: "memory");

        // ---- synchronized A-phase (R9-identical; frags scoped locally) ----
        f32x4 a00 = {0.f, 0.f, 0.f, 0.f};
        f32x4 a01 = a00, a10 = a00, a11 = a00;
        if (s >= 1 && s < 256) {
            const size_t pb = ((size_t)(s - 1) << 14) + ((size_t)bc << 10) + (wv << 8);
            const unsigned short* ph = hhi + pb;
            const unsigned short* pl = hlo + pb;
            bf16x8 ahi[8], alo[8];
#pragma unroll
            for (int ck = 0; ck < 8; ++ck) {
                ahi[ck] = *(const bf16x8*)(ph + (ck << 5) + (quad << 3));
                alo[ck] = *(const bf16x8*)(pl + (ck << 5) + (quad << 3));
            }
#pragma unroll
            for (int ck = 0; ck < 8; ++ck) {
                if (ck & 1) {
                    a10 = MFMA16(ahi[ck], Whi[ck], a10);
                    a11 = MFMA16(ahi[ck], Wmi[ck], a11);
                    a10 = MFMA16(ahi[ck], Wlo[ck], a10);
                    a11 = MFMA16(alo[ck], Whi[ck], a11);
                    a10 = MFMA16(alo[ck], Wmi[ck], a10);
                } else {
                    a00 = MFMA16(ahi[ck], Whi[ck], a00);
                    a01 = MFMA16(ahi[ck], Wmi[ck], a01);
                    a00 = MFMA16(ahi[ck], Wlo[ck], a00);
                    a01 = MFMA16(alo[ck], Whi[ck], a01);
                    a00 = MFMA16(alo[ck], Wmi[ck], a00);
                }
            }
        }
        f32x4 acc = (a00 + a01) + (a10 + a11);
        *(f32x4*)&red[wv][lane][0] = acc;
        __syncthreads();

        // ---- post-barrier-2 (overlapped) region ----
        if (wv == 0 && s < 256) {
            // R9 finish
            f32x4 s0 = *(const f32x4*)&red[0][lane][0];
            f32x4 s1 = *(const f32x4*)&red[1][lane][0];
            f32x4 s2 = *(const f32x4*)&red[2][lane][0];
            f32x4 s3 = *(const f32x4*)&red[3][lane][0];
            f32x4 sv = (s0 + s1) + (s2 + s3);
#pragma unroll
            for (int r = 0; r < 4; ++r)
                gsh[(quad << 2) + r][bc] = sv[r] + pr[r];

            const int b2 = lane >> 2, jl2 = lane & 3;
            float fg = sigmoidf_(gsh[b2][jl2]);
            float ig = sigmoidf_(gsh[b2][4 + jl2]);
            float pg = tanhf_(gsh[b2][8 + jl2]);
            float og = sigmoidf_(gsh[b2][12 + jl2]);
            creg = fg * creg + ig * pg;
            float h = tanhf_(creg) * og;

            const int j = (wg << 2) + jl2;
            unsigned short hh = f2bf_rn(h);
            unsigned short hl = f2bf_rn(h - bf2f(hh));
            size_t pidx = ((size_t)s << 14) + ((size_t)b2 << 10) + j;
            __hip_atomic_store(&hhi[pidx], hh, __ATOMIC_RELAXED, __HIP_MEMORY_SCOPE_AGENT);
            __hip_atomic_store(&hlo[pidx], hl, __ATOMIC_RELAXED, __HIP_MEMORY_SCOPE_AGENT);
            if (is_last && s == 255) final_out[((size_t)b2 << 10) + j] = h;

            __builtin_amdgcn_s_waitcnt(0);
            if (lane == 0)
                __hip_atomic_fetch_add(&ctr_l1[((s << 4) + (wg >> 4)) << 5], 1,
                                       __ATOMIC_RELAXED,
                                       __HIP_MEMORY_SCOPE_AGENT);
        } else if (wv == 1 && has_next && s >= 2) {
            // reduce previous redP plane -> pre[s-2] in place (own columns;
            // this dispatch's reader of pre[s-2] finished 2 barriers ago)
            f32x4 q0 = *(const f32x4*)&redP[(s - 1) & 1][0][lane][0];
            f32x4 q1 = *(const f32x4*)&redP[(s - 1) & 1][1][lane][0];
            f32x4 q2 = *(const f32x4*)&redP[(s - 1) & 1][2][lane][0];
            f32x4 q3 = *(const f32x4*)&redP[(s - 1) & 1][3][lane][0];
            f32x4 qm = (q0 + q1) + (q2 + q3);
            float* pw = pre + ((size_t)(s - 2) << 16) + ((size_t)g << 10) + col;
#pragma unroll
            for (int r = 0; r < 4; ++r)
                pw[(size_t)((quad << 2) + r) << 12] = qm[r] + biasvN;
        }

        // next-layer pre MFMAs, overlapping finish/drain/poll. Frags are
        // RELOADED per-ck (L1/L2-hot; off critical path) to cap liveness.
        if (has_next && s >= 1 && s <= 256) {
            const size_t pb = ((size_t)(s - 1) << 14) + ((size_t)bc << 10) + (wv << 8);
            const unsigned short* ph = hhi + pb;
            const unsigned short* pl = hlo + pb;
            f32x4 p00 = {0.f, 0.f, 0.f, 0.f};
            f32x4 p01 = p00, p10 = p00, p11 = p00;
#pragma unroll
            for (int ck = 0; ck < 8; ++ck) {
                bf16x8 ah = *(const bf16x8*)(ph + (ck << 5) + (quad << 3));
                bf16x8 al = *(const bf16x8*)(pl + (ck << 5) + (quad << 3));
                if (ck & 1) {
                    p10 = MFMA16(ah, WXh[ck], p10);
                    p11 = MFMA16(ah, WXm[ck], p11);
                    p10 = MFMA16(ah, WXl[ck], p10);
                    p11 = MFMA16(al, WXh[ck], p11);
                    p10 = MFMA16(al, WXm[ck], p10);
                } else {
                    p00 = MFMA16(ah, WXh[ck], p00);
                    p01 = MFMA16(ah, WXm[ck], p01);
                    p00 = MFMA16(ah, WXl[ck], p00);
                    p01 = MFMA16(al, WXh[ck], p01);
                    p00 = MFMA16(al, WXm[ck], p00);
                }
            }
            *(f32x4*)&redP[s & 1][wv][lane][0] = (p00 + p01) + (p10 + p11);
        }
    }
}

// ---------------------------------------------------------------------------
extern "C" void kernel_launch(void* const* d_in, const int* in_sizes, int n_in,
                              void* d_out, int out_size, void* d_ws, size_t ws_size,
                              hipStream_t stream)
{
    (void)in_sizes; (void)n_in; (void)out_size; (void)ws_size;

    const float* x    = (const float*)d_in[0];   // [16][256][256]
    const float* Wh   = (const float*)d_in[1];   // [4][4][1024][1024]
    const float* Wx0  = (const float*)d_in[2];   // [4][256][1024]
    const float* Wx   = (const float*)d_in[3];   // [3][4][1024][1024]
    const float* bias = (const float*)d_in[4];   // [4][4][1024]

    float* pre  = (float*)d_ws;                    // 16,777,216 f
    float* seqA = pre + 16777216;                  // 4,194,304 f
    float* seqB = seqA + 4194304;                  // 4,194,304 f
    unsigned short* hhi = (unsigned short*)(seqB + 4194304);   // 4,194,304 u16
    unsigned short* hlo = hhi + 4194304;                       // 4,194,304 u16
    int* ctr = (int*)(hlo + 4194304);
    const size_t FB_PL = 256 * 16 * 32;   // per layer

    float* fout = (float*)d_out;

    hipMemsetAsync(ctr, 0, 4 * FB_PL * sizeof(int), stream);

    const dim3 blk(256);
    const dim3 ggrid(32, 32);
    const size_t WLAYER = (size_t)4 * 1024 * 1024;

    // capture-safe guard: can the fused kernel co-reside 1 block/CU?
    int nb = 0;
    if (hipOccupancyMaxActiveBlocksPerMultiprocessor(&nb, lstm_scan_fused, 256, 0)
        != hipSuccess) nb = 0;

    if (nb >= 1) {
        // -------- fused path: 1 pre_gemm + 4 fused scans --------
        pre_gemm<<<ggrid, blk, 0, stream>>>(x, Wx0, bias, pre, 256);
        for (int l = 0; l < 4; ++l) {
            float* p        = pre;
            const float* wh = Wh + (size_t)l * WLAYER;
            const float* wxn = Wx + (size_t)((l < 3) ? l : 2) * WLAYER; // dummy l=3
            const float* bn  = bias + (size_t)((l < 3) ? (l + 1) : 3) * 4096;
            int* pl1 = ctr + (size_t)l * FB_PL;
            int last  = (l == 3);
            int hnext = (l < 3);
            void* args[] = { (void*)&p, (void*)&wh, (void*)&wxn, (void*)&bn,
                             (void*)&hhi, (void*)&hlo, (void*)&pl1,
                             (void*)&fout, (void*)&last, (void*)&hnext };
            hipLaunchCooperativeKernel((void*)lstm_scan_fused, dim3(256), blk,
                                       args, 0, stream);
        }
    } else {
        // -------- fallback: EXACT R9 path (proven 6853us) --------
        for (int l = 0; l < 4; ++l) {
            const float* inp = (l == 0) ? x : ((l & 1) ? seqA : seqB);
            float* outp      = (l & 1) ? seqB : seqA;
            const float* wx  = (l == 0) ? Wx0 : (Wx + (size_t)(l - 1) * WLAYER);
            int K            = (l == 0) ? 256 : 1024;

            pre_gemm<<<ggrid, blk, 0, stream>>>(inp, wx, bias + (size_t)l * 4096, pre, K);

            const float* p = pre;
            const float* wh = Wh + (size_t)l * WLAYER;
            float* so = outp;
            int* pl1 = ctr + (size_t)l * FB_PL;
            int last = (l == 3);
            void* args[] = { (void*)&p, (void*)&wh, (void*)&so, (void*)&hhi,
                             (void*)&hlo, (void*)&pl1, (void*)&fout, (void*)&last };
            hipLaunchCooperativeKernel((void*)lstm_scan, dim3(256), blk, args, 0, stream);
        }
    }
}

// Round 11
// 6745.272 us; speedup vs baseline: 1.0210x; 1.0122x over previous
//
#include <hip/hip_runtime.h>

// B=16, T=256, IN=256, H=1024, L=4, 4 gates -> 4H=4096.
// R14: shadow-pipelined layer-pair wavefront (520 seq steps vs 1032).
// R13 proved extra MFMA units ride FREE in the post-barrier-2 shadow
// (fused scan 5.3us/step with 2x MFMA work). R14 puts BOTH B-units there:
//   SYNC(s):     A-MFMA(t=s) only                     [1 unit, short]
//   SHADOW-1(s): wave0 A-finish(s) (drain+ctrA early);
//                all: P-MFMA(u=s-1) + B-MFMA(u=s-4);  wave2 P-reduce(s-3)
//   barrier3
//   SHADOW-2(s): wave1 B-finish(u=s-4) -> ctrB        [hides under next poll]
// Buffers: redP 3-ring ((s-1)%3 vs (s-3)%3 disjoint), redB/ring 2-deep,
// >=2-barrier write->read separation everywhere. Dual counter planes
// (R10-proven poll split). 512 thr / 8 waves = R11's proven reg envelope.
// Occupancy-guarded (5/5 unguarded fat coop launches silently no-op'd);
// verbatim-R9 fallback (proven 6853us).
//
// ws (114.1 MB): pre 16,777,216 f | seqA 4,194,304 f
//   | reg2 4,194,304 f (fallback: seqB | pair: hBhi+hBlo)
//   | hAhi/hAlo 4,194,304 u16 each | ctr 4 x 131072 ints

typedef float f32x4 __attribute__((ext_vector_type(4)));
typedef short bf16x8 __attribute__((ext_vector_type(8)));

__device__ __forceinline__ unsigned short f2bf_rn(float x) {
    unsigned int u = __float_as_uint(x);
    u += 0x7FFFu + ((u >> 16) & 1u);          // round-to-nearest-even
    return (unsigned short)(u >> 16);
}
__device__ __forceinline__ float bf2f(unsigned short s) {
    return __uint_as_float(((unsigned int)s) << 16);
}
__device__ __forceinline__ float sigmoidf_(float x) { return 1.0f / (1.0f + __expf(-x)); }
__device__ __forceinline__ float tanhf_(float x) {
    float e = __expf(2.0f * x);
    return 1.0f - 2.0f / (e + 1.0f);
}

#define MFMA16(a, b, c) __builtin_amdgcn_mfma_f32_16x16x32_bf16((a), (b), (c), 0, 0, 0)

// ---------------------------------------------------------------------------
// pre GEMM (proven, unchanged): 128x128 tile, BK=16, fp32.
// ---------------------------------------------------------------------------
__global__ __launch_bounds__(256)
void pre_gemm(const float* __restrict__ A, const float* __restrict__ W,
              const float* __restrict__ bias, float* __restrict__ out, int K)
{
    __shared__ float As[16][132];
    __shared__ float Bs[16][132];

    const int tid = threadIdx.x;
    const int m0 = blockIdx.y << 7;
    const int n0 = blockIdx.x << 7;
    const int g  = n0 >> 10;
    const int jb = n0 & 1023;
    const float* Wg = W + (size_t)g * K * 1024 + jb;

    const int tx = tid & 15;
    const int ty = tid >> 4;
    const int alk = tid & 15;
    const int alm = tid >> 4;
    const int bln = tid & 127;
    const int blkk = tid >> 7;

    float acc[8][8];
#pragma unroll
    for (int i = 0; i < 8; ++i)
#pragma unroll
        for (int j = 0; j < 8; ++j) acc[i][j] = 0.f;

    for (int k0 = 0; k0 < K; k0 += 16) {
        __syncthreads();
#pragma unroll
        for (int r = 0; r < 8; ++r) {
            int m = alm + (r << 4);
            As[alk][m] = A[(size_t)(m0 + m) * K + (k0 + alk)];
        }
#pragma unroll
        for (int r = 0; r < 8; ++r) {
            int kk = blkk + (r << 1);
            Bs[kk][bln] = Wg[(size_t)(k0 + kk) * 1024 + bln];
        }
        __syncthreads();
#pragma unroll
        for (int k = 0; k < 16; ++k) {
            float a[8], bb[8];
            *(f32x4*)&a[0]  = *(const f32x4*)&As[k][ty << 2];
            *(f32x4*)&a[4]  = *(const f32x4*)&As[k][64 + (ty << 2)];
            *(f32x4*)&bb[0] = *(const f32x4*)&Bs[k][tx << 2];
            *(f32x4*)&bb[4] = *(const f32x4*)&Bs[k][64 + (tx << 2)];
#pragma unroll
            for (int i = 0; i < 8; ++i)
#pragma unroll
                for (int j = 0; j < 8; ++j)
                    acc[i][j] = fmaf(a[i], bb[j], acc[i][j]);
        }
    }

    float bj[8];
#pragma unroll
    for (int j = 0; j < 8; ++j) {
        int nloc = (j < 4) ? ((tx << 2) + j) : (64 + (tx << 2) + (j - 4));
        bj[j] = bias[n0 + nloc];
    }
#pragma unroll
    for (int i = 0; i < 8; ++i) {
        int mloc = (i < 4) ? ((ty << 2) + i) : (64 + (ty << 2) + (i - 4));
        int m = m0 + mloc;
        int bidx = m >> 8;
        int tt   = m & 255;
        float* orow = out + ((size_t)((tt << 4) + bidx) << 12) + n0;
#pragma unroll
        for (int j = 0; j < 8; ++j) {
            int nloc = (j < 4) ? ((tx << 2) + j) : (64 + (tx << 2) + (j - 4));
            orow[nloc] = acc[i][j] + bj[j];
        }
    }
}

// ---------------------------------------------------------------------------
// R9 single-layer scan (proven at 6853us total). VERBATIM fallback.
// ---------------------------------------------------------------------------
__global__ __launch_bounds__(256)
void lstm_scan(const float* __restrict__ pre,
               const float* __restrict__ Wh,
               float* __restrict__ seq_out,
               unsigned short* __restrict__ hhi,
               unsigned short* __restrict__ hlo,
               int* __restrict__ ctr_l1,
               float* __restrict__ final_out,
               int is_last)
{
    const int wg   = blockIdx.x;
    const int tid  = threadIdx.x;
    const int wv   = tid >> 6;
    const int lane = tid & 63;
    const int bc   = lane & 15;
    const int quad = lane >> 4;

    __shared__ float red[4][64][4];
    __shared__ float gsh[16][17];

    const int g   = bc >> 2;
    const int col = (wg << 2) + (bc & 3);
    bf16x8 Whi[8], Wmi[8], Wlo[8];
#pragma unroll
    for (int ck = 0; ck < 8; ++ck) {
#pragma unroll
        for (int j = 0; j < 8; ++j) {
            int k = (wv << 8) + (ck << 5) + (quad << 3) + j;
            float w = Wh[((size_t)g << 20) + ((size_t)k << 10) + col];
            unsigned short hi = f2bf_rn(w);
            float r1 = w - bf2f(hi);
            unsigned short mi = f2bf_rn(r1);
            float r2 = r1 - bf2f(mi);
            unsigned short lo = f2bf_rn(r2);
            Whi[ck][j] = (short)hi;
            Wmi[ck][j] = (short)mi;
            Wlo[ck][j] = (short)lo;
        }
    }

    float creg = 0.f;
    int dead = 0;

    for (int t = 0; t < 256; ++t) {
        float pr[4];
        if (wv == 0) {
            const float* pp = pre + ((size_t)t << 16) + ((size_t)(bc >> 2) << 10)
                              + (wg << 2) + (bc & 3);
#pragma unroll
            for (int r = 0; r < 4; ++r)
                pr[r] = pp[(size_t)((quad << 2) + r) << 12];
        }

        if (t > 0 && wv == 0 && !dead) {
            const int* lb = ctr_l1 + (((t - 1) << 4) << 5);
            bool done = (lane >= 16);
            const int gi5 = (lane & 15) << 5;
            int guard = 0;
            for (;;) {
                if (!done)
                    done = __hip_atomic_load(lb + gi5, __ATOMIC_RELAXED,
                                             __HIP_MEMORY_SCOPE_AGENT) >= 16;
                if (__all(done)) break;
                __builtin_amdgcn_s_sleep(1);
                if (++guard > (1 << 15)) { dead = 1; break; }
            }
        }
        __syncthreads();
        asm volatile("" ::: "memory");

        f32x4 a00 = {0.f, 0.f, 0.f, 0.f};
        f32x4 a01 = a00, a10 = a00, a11 = a00;
        if (t > 0) {
            const size_t pb = ((size_t)(t - 1) << 14) + ((size_t)bc << 10) + (wv << 8);
            const unsigned short* ph = hhi + pb;
            const unsigned short* pl = hlo + pb;
            bf16x8 ahi[8], alo[8];
#pragma unroll
            for (int ck = 0; ck < 8; ++ck) {
                ahi[ck] = *(const bf16x8*)(ph + (ck << 5) + (quad << 3));
                alo[ck] = *(const bf16x8*)(pl + (ck << 5) + (quad << 3));
            }
#pragma unroll
            for (int ck = 0; ck < 8; ++ck) {
                if (ck & 1) {
                    a10 = MFMA16(ahi[ck], Whi[ck], a10);
                    a11 = MFMA16(ahi[ck], Wmi[ck], a11);
                    a10 = MFMA16(ahi[ck], Wlo[ck], a10);
                    a11 = MFMA16(alo[ck], Whi[ck], a11);
                    a10 = MFMA16(alo[ck], Wmi[ck], a10);
                } else {
                    a00 = MFMA16(ahi[ck], Whi[ck], a00);
                    a01 = MFMA16(ahi[ck], Wmi[ck], a01);
                    a00 = MFMA16(ahi[ck], Wlo[ck], a00);
                    a01 = MFMA16(alo[ck], Whi[ck], a01);
                    a00 = MFMA16(alo[ck], Wmi[ck], a00);
                }
            }
        }
        f32x4 acc = (a00 + a01) + (a10 + a11);
        *(f32x4*)&red[wv][lane][0] = acc;
        __syncthreads();

        if (wv == 0) {
            f32x4 s0 = *(const f32x4*)&red[0][lane][0];
            f32x4 s1 = *(const f32x4*)&red[1][lane][0];
            f32x4 s2 = *(const f32x4*)&red[2][lane][0];
            f32x4 s3 = *(const f32x4*)&red[3][lane][0];
            f32x4 s = (s0 + s1) + (s2 + s3);
#pragma unroll
            for (int r = 0; r < 4; ++r)
                gsh[(quad << 2) + r][bc] = s[r] + pr[r];

            const int b2 = lane >> 2, jl2 = lane & 3;
            float fg = sigmoidf_(gsh[b2][jl2]);
            float ig = sigmoidf_(gsh[b2][4 + jl2]);
            float pg = tanhf_(gsh[b2][8 + jl2]);
            float og = sigmoidf_(gsh[b2][12 + jl2]);
            creg = fg * creg + ig * pg;
            float h = tanhf_(creg) * og;

            const int j = (wg << 2) + jl2;
            unsigned short hh = f2bf_rn(h);
            unsigned short hl = f2bf_rn(h - bf2f(hh));
            size_t pidx = ((size_t)t << 14) + ((size_t)b2 << 10) + j;
            __hip_atomic_store(&hhi[pidx], hh, __ATOMIC_RELAXED, __HIP_MEMORY_SCOPE_AGENT);
            __hip_atomic_store(&hlo[pidx], hl, __ATOMIC_RELAXED, __HIP_MEMORY_SCOPE_AGENT);
            if (is_last && t == 255) final_out[((size_t)b2 << 10) + j] = h;

            __builtin_amdgcn_s_waitcnt(0);
            if (lane == 0)
                __hip_atomic_fetch_add(&ctr_l1[((t << 4) + (wg >> 4)) << 5], 1,
                                       __ATOMIC_RELAXED,
                                       __HIP_MEMORY_SCOPE_AGENT);

            if (!is_last)
                seq_out[((size_t)((b2 << 8) + t) << 10) + j] = h;
        }
    }
}

// ---------------------------------------------------------------------------
// Shadow-pipelined layer-pair. 256 wgs x 512 threads (8 waves, k-slice 128).
// Timeline at global step s (t_A = s, u_B = s-4):
//   poll[ctrA(s-1), ctrB(s-5)] -> B1 -> A-MFMA(s) -> B2 ->
//   SHADOW1{ w0:A-finish(s); all:P-MFMA(s-1)+B-MFMA(s-4); w2:P-reduce(s-3) }
//   -> B3 -> SHADOW2{ w1:B-finish(s-4) }  (overlaps next step's poll)
// ---------------------------------------------------------------------------
__global__ __launch_bounds__(512)
void lstm_pair(const float* __restrict__ preA,   // [256][16][4096]
               const float* __restrict__ WhA,    // [4][1024][1024]
               const float* __restrict__ WhB,    // [4][1024][1024]
               const float* __restrict__ WxB,    // [4][1024][1024]
               const float* __restrict__ biasB,  // [4][1024]
               float* __restrict__ seq_out,      // [16][256][1024] (!is_last)
               unsigned short* __restrict__ hAhi, unsigned short* __restrict__ hAlo,
               unsigned short* __restrict__ hBhi, unsigned short* __restrict__ hBlo,
               int* __restrict__ ctrA,           // [256 t][16 grp] stride-32
               int* __restrict__ ctrB,           // [256 u][16 grp] stride-32
               float* __restrict__ final_out,    // [16][1024]
               int is_last)
{
    const int wg   = blockIdx.x;
    const int tid  = threadIdx.x;
    const int wv   = tid >> 6;        // 8 waves; wave owns k [wv*128, +128)
    const int lane = tid & 63;
    const int bc   = lane & 15;
    const int quad = lane >> 4;

    __shared__ float redA[8][64][4];     // A-scan reduction
    __shared__ float redP[3][8][64][4];  // B-pre reduction, 3-ring
    __shared__ float redB[2][8][64][4];  // B-scan reduction, 2-deep
    __shared__ float gsh[2][16][17];     // gate exchange [A/B]
    __shared__ float ring[2][16][17];    // preB(u) ring, 2-deep

    const int g   = bc >> 2;
    const int col = (wg << 2) + (bc & 3);

    // one-time: 3-term bf16 splits, 4 ck-blocks per wave (R11 envelope)
    bf16x8 WAh[4], WAm[4], WAl[4];
    bf16x8 WBh[4], WBm[4], WBl[4];
    bf16x8 WXh[4], WXm[4], WXl[4];
#pragma unroll
    for (int ck = 0; ck < 4; ++ck) {
#pragma unroll
        for (int j = 0; j < 8; ++j) {
            const int k = (wv << 7) + (ck << 5) + (quad << 3) + j;
            const size_t widx = ((size_t)g << 20) + ((size_t)k << 10) + col;
            {
                float w = WhA[widx];
                unsigned short hi = f2bf_rn(w); float r1 = w - bf2f(hi);
                unsigned short mi = f2bf_rn(r1); float r2 = r1 - bf2f(mi);
                WAh[ck][j] = (short)hi; WAm[ck][j] = (short)mi;
                WAl[ck][j] = (short)f2bf_rn(r2);
            }
            {
                float w = WhB[widx];
                unsigned short hi = f2bf_rn(w); float r1 = w - bf2f(hi);
                unsigned short mi = f2bf_rn(r1); float r2 = r1 - bf2f(mi);
                WBh[ck][j] = (short)hi; WBm[ck][j] = (short)mi;
                WBl[ck][j] = (short)f2bf_rn(r2);
            }
            {
                float w = WxB[widx];
                unsigned short hi = f2bf_rn(w); float r1 = w - bf2f(hi);
                unsigned short mi = f2bf_rn(r1); float r2 = r1 - bf2f(mi);
                WXh[ck][j] = (short)hi; WXm[ck][j] = (short)mi;
                WXl[ck][j] = (short)f2bf_rn(r2);
            }
        }
    }
    const float biasv = biasB[((size_t)g << 10) + col];

    float cregA = 0.f;   // wave0 lanes: layer-A cell
    float cregB = 0.f;   // wave1 lanes: layer-B cell
    int dead = 0;

    for (int s = 0; s < 260; ++s) {
        // prefetch layer-A pre (overlaps the poll)
        float pr[4];
        if (wv == 0 && s < 256) {
            const float* pp = preA + ((size_t)s << 16) + ((size_t)g << 10) + col;
#pragma unroll
            for (int r = 0; r < 4; ++r)
                pr[r] = pp[(size_t)((quad << 2) + r) << 12];
        }

        if (s >= 1 && wv == 0 && !dead) {
            // lanes 0-15: ctrA[s-1] (needed while A/P consume h_A: s<=256)
            // lanes 16-31: ctrB[s-5] (needed while B consumes h_B: 5<=s<=259)
            bool done;
            const int gi = lane & 15;
            const int* wp;
            if (lane < 16)      { done = (s > 256); wp = ctrA + (((s - 1) << 4) + gi) * 32; }
            else if (lane < 32) { done = (s < 5);   wp = ctrB + (((s - 5) << 4) + gi) * 32; }
            else                { done = true;      wp = ctrA; }
            int guard = 0;
            for (;;) {
                if (!done)
                    done = __hip_atomic_load(wp, __ATOMIC_RELAXED,
                                             __HIP_MEMORY_SCOPE_AGENT) >= 16;
                if (__all(done)) break;
                __builtin_amdgcn_s_sleep(1);
                if (++guard > (1 << 15)) { dead = 1; break; }
            }
        }
        __syncthreads();                                   // barrier 1
        asm volatile("" ::: "memory");

        // ---- SYNC: A-MFMA(t=s) only ----
        f32x4 a0 = {0.f, 0.f, 0.f, 0.f}, a1 = a0;
        if (s >= 1 && s <= 255) {
            const size_t pb = ((size_t)(s - 1) << 14) + ((size_t)bc << 10) + (wv << 7);
            const unsigned short* ph = hAhi + pb;
            const unsigned short* pl = hAlo + pb;
#pragma unroll
            for (int ck = 0; ck < 4; ++ck) {
                bf16x8 ah = *(const bf16x8*)(ph + (ck << 5) + (quad << 3));
                bf16x8 al = *(const bf16x8*)(pl + (ck << 5) + (quad << 3));
                if (ck & 1) {
                    a1 = MFMA16(ah, WAh[ck], a1);
                    a1 = MFMA16(ah, WAm[ck], a1);
                    a1 = MFMA16(ah, WAl[ck], a1);
                    a1 = MFMA16(al, WAh[ck], a1);
                    a1 = MFMA16(al, WAm[ck], a1);
                } else {
                    a0 = MFMA16(ah, WAh[ck], a0);
                    a0 = MFMA16(ah, WAm[ck], a0);
                    a0 = MFMA16(ah, WAl[ck], a0);
                    a0 = MFMA16(al, WAh[ck], a0);
                    a0 = MFMA16(al, WAm[ck], a0);
                }
            }
        }
        *(f32x4*)&redA[wv][lane][0] = a0 + a1;
        __syncthreads();                                   // barrier 2

        // ---- SHADOW-1 ----
        if (wv == 0) {
            if (s <= 255) {                                // A-finish(t=s)
                f32x4 sm = {0.f, 0.f, 0.f, 0.f};
#pragma unroll
                for (int w = 0; w < 8; ++w)
                    sm += *(const f32x4*)&redA[w][lane][0];
#pragma unroll
                for (int r = 0; r < 4; ++r)
                    gsh[0][(quad << 2) + r][bc] = sm[r] + pr[r];

                const int b2 = lane >> 2, jl2 = lane & 3;
                float fg = sigmoidf_(gsh[0][b2][jl2]);
                float ig = sigmoidf_(gsh[0][b2][4 + jl2]);
                float pg = tanhf_(gsh[0][b2][8 + jl2]);
                float og = sigmoidf_(gsh[0][b2][12 + jl2]);
                cregA = fg * cregA + ig * pg;
                float h = tanhf_(cregA) * og;
                const int j = (wg << 2) + jl2;
                unsigned short hh = f2bf_rn(h);
                unsigned short hl = f2bf_rn(h - bf2f(hh));
                size_t pidx = ((size_t)s << 14) + ((size_t)b2 << 10) + j;
                __hip_atomic_store(&hAhi[pidx], hh, __ATOMIC_RELAXED, __HIP_MEMORY_SCOPE_AGENT);
                __hip_atomic_store(&hAlo[pidx], hl, __ATOMIC_RELAXED, __HIP_MEMORY_SCOPE_AGENT);
                __builtin_amdgcn_s_waitcnt(0);
                if (lane == 0)
                    __hip_atomic_fetch_add(&ctrA[((s << 4) + (wg >> 4)) << 5], 1,
                                           __ATOMIC_RELAXED,
                                           __HIP_MEMORY_SCOPE_AGENT);
            }
        } else if (wv == 2) {
            if (s >= 3 && s <= 258) {                      // P-reduce(u=s-3)
                const int u = s - 3;
                f32x4 qm = {0.f, 0.f, 0.f, 0.f};
#pragma unroll
                for (int w = 0; w < 8; ++w)
                    qm += *(const f32x4*)&redP[u % 3][w][lane][0];
#pragma unroll
                for (int r = 0; r < 4; ++r)
                    ring[u & 1][(quad << 2) + r][bc] = qm[r] + biasv;
            }
        }

        // P-MFMA(u=s-1): reload h_A(s-1) frags (L2-hot), all waves
        if (s >= 1 && s <= 256) {
            const size_t pb = ((size_t)(s - 1) << 14) + ((size_t)bc << 10) + (wv << 7);
            const unsigned short* ph = hAhi + pb;
            const unsigned short* pl = hAlo + pb;
            f32x4 p0 = {0.f, 0.f, 0.f, 0.f}, p1 = p0;
#pragma unroll
            for (int ck = 0; ck < 4; ++ck) {
                bf16x8 ah = *(const bf16x8*)(ph + (ck << 5) + (quad << 3));
                bf16x8 al = *(const bf16x8*)(pl + (ck << 5) + (quad << 3));
                if (ck & 1) {
                    p1 = MFMA16(ah, WXh[ck], p1);
                    p1 = MFMA16(ah, WXm[ck], p1);
                    p1 = MFMA16(ah, WXl[ck], p1);
                    p1 = MFMA16(al, WXh[ck], p1);
                    p1 = MFMA16(al, WXm[ck], p1);
                } else {
                    p0 = MFMA16(ah, WXh[ck], p0);
                    p0 = MFMA16(ah, WXm[ck], p0);
                    p0 = MFMA16(ah, WXl[ck], p0);
                    p0 = MFMA16(al, WXh[ck], p0);
                    p0 = MFMA16(al, WXm[ck], p0);
                }
            }
            *(f32x4*)&redP[(s - 1) % 3][wv][lane][0] = p0 + p1;
        }

        // B-MFMA(u=s-4): consume h_B(u-1), all waves
        if (s >= 4 && s <= 259) {
            const int u = s - 4;
            f32x4 b0 = {0.f, 0.f, 0.f, 0.f}, b1 = b0;
            if (u >= 1) {
                const size_t pb = ((size_t)(u - 1) << 14) + ((size_t)bc << 10) + (wv << 7);
                const unsigned short* ph = hBhi + pb;
                const unsigned short* pl = hBlo + pb;
#pragma unroll
                for (int ck = 0; ck < 4; ++ck) {
                    bf16x8 bh = *(const bf16x8*)(ph + (ck << 5) + (quad << 3));
                    bf16x8 bl = *(const bf16x8*)(pl + (ck << 5) + (quad << 3));
                    if (ck & 1) {
                        b1 = MFMA16(bh, WBh[ck], b1);
                        b1 = MFMA16(bh, WBm[ck], b1);
                        b1 = MFMA16(bh, WBl[ck], b1);
                        b1 = MFMA16(bl, WBh[ck], b1);
                        b1 = MFMA16(bl, WBm[ck], b1);
                    } else {
                        b0 = MFMA16(bh, WBh[ck], b0);
                        b0 = MFMA16(bh, WBm[ck], b0);
                        b0 = MFMA16(bh, WBl[ck], b0);
                        b0 = MFMA16(bl, WBh[ck], b0);
                        b0 = MFMA16(bl, WBm[ck], b0);
                    }
                }
            }
            *(f32x4*)&redB[u & 1][wv][lane][0] = b0 + b1;
        }
        __syncthreads();                                   // barrier 3

        // ---- SHADOW-2: wave1 B-finish(u=s-4), overlaps next step's poll ----
        if (wv == 1 && s >= 4 && s <= 259) {
            const int u = s - 4;
            f32x4 sm = {0.f, 0.f, 0.f, 0.f};
#pragma unroll
            for (int w = 0; w < 8; ++w)
                sm += *(const f32x4*)&redB[u & 1][w][lane][0];
#pragma unroll
            for (int r = 0; r < 4; ++r)
                gsh[1][(quad << 2) + r][bc] =
                    sm[r] + ring[u & 1][(quad << 2) + r][bc];

            const int b2 = lane >> 2, jl2 = lane & 3;
            float fg = sigmoidf_(gsh[1][b2][jl2]);
            float ig = sigmoidf_(gsh[1][b2][4 + jl2]);
            float pg = tanhf_(gsh[1][b2][8 + jl2]);
            float og = sigmoidf_(gsh[1][b2][12 + jl2]);
            cregB = fg * cregB + ig * pg;
            float h = tanhf_(cregB) * og;
            const int j = (wg << 2) + jl2;
            unsigned short hh = f2bf_rn(h);
            unsigned short hl = f2bf_rn(h - bf2f(hh));
            size_t pidx = ((size_t)u << 14) + ((size_t)b2 << 10) + j;
            __hip_atomic_store(&hBhi[pidx], hh, __ATOMIC_RELAXED, __HIP_MEMORY_SCOPE_AGENT);
            __hip_atomic_store(&hBlo[pidx], hl, __ATOMIC_RELAXED, __HIP_MEMORY_SCOPE_AGENT);
            __builtin_amdgcn_s_waitcnt(0);
            if (lane == 0)
                __hip_atomic_fetch_add(&ctrB[((u << 4) + (wg >> 4)) << 5], 1,
                                       __ATOMIC_RELAXED,
                                       __HIP_MEMORY_SCOPE_AGENT);
            if (!is_last)
                seq_out[(((size_t)(b2 << 8) + u) << 10) + j] = h;   // next dispatch
            if (is_last && u == 255)
                final_out[((size_t)b2 << 10) + j] = h;
        }
    }
}

// ---------------------------------------------------------------------------
extern "C" void kernel_launch(void* const* d_in, const int* in_sizes, int n_in,
                              void* d_out, int out_size, void* d_ws, size_t ws_size,
                              hipStream_t stream)
{
    (void)in_sizes; (void)n_in; (void)out_size; (void)ws_size;

    const float* x    = (const float*)d_in[0];   // [16][256][256]
    const float* Wh   = (const float*)d_in[1];   // [4][4][1024][1024]
    const float* Wx0  = (const float*)d_in[2];   // [4][256][1024]
    const float* Wx   = (const float*)d_in[3];   // [3][4][1024][1024]
    const float* bias = (const float*)d_in[4];   // [4][4][1024]

    float* pre  = (float*)d_ws;                    // 16,777,216 f
    float* seqA = pre + 16777216;                  // 4,194,304 f
    float* reg2 = seqA + 4194304;                  // 4,194,304 f (aliased)
    unsigned short* hAhi = (unsigned short*)(reg2 + 4194304);  // 4,194,304 u16
    unsigned short* hAlo = hAhi + 4194304;                     // 4,194,304 u16
    int* ctr = (int*)(hAlo + 4194304);
    const size_t PL = 256 * 16 * 32;   // one counter plane

    float* fout = (float*)d_out;
    const dim3 blk(256);
    const dim3 blkP(512);
    const dim3 ggrid(32, 32);
    const size_t WLAYER = (size_t)4 * 1024 * 1024;

    // capture-safe guard (rule: never enqueue an unguarded fat coop launch)
    int nb = 0;
    if (hipOccupancyMaxActiveBlocksPerMultiprocessor(&nb, lstm_pair, 512, 0)
        != hipSuccess) nb = 0;

    hipMemsetAsync(ctr, 0, 4 * PL * sizeof(int), stream);

    if (nb >= 1) {
        // -------- pair path: 2 pre_gemm + 2 shadow-pipelined pairs --------
        unsigned short* hBhi = (unsigned short*)reg2;
        unsigned short* hBlo = hBhi + 4194304;

        pre_gemm<<<ggrid, blk, 0, stream>>>(x, Wx0, bias, pre, 256);
        for (int p01 = 0; p01 < 2; ++p01) {
            const float* p   = pre;
            const float* whA = Wh + (size_t)(2 * p01) * WLAYER;
            const float* whB = Wh + (size_t)(2 * p01 + 1) * WLAYER;
            const float* wxB = Wx + (size_t)(2 * p01) * WLAYER;      // layer 1 / 3
            const float* bB  = bias + (size_t)(2 * p01 + 1) * 4096;
            float* so = seqA;
            int* cA = ctr + (size_t)(2 * p01) * PL;
            int* cB = cA + PL;
            int last = (p01 == 1);
            void* args[] = { (void*)&p, (void*)&whA, (void*)&whB, (void*)&wxB,
                             (void*)&bB, (void*)&so, (void*)&hAhi, (void*)&hAlo,
                             (void*)&hBhi, (void*)&hBlo, (void*)&cA, (void*)&cB,
                             (void*)&fout, (void*)&last };
            hipLaunchCooperativeKernel((void*)lstm_pair, dim3(256), blkP, args, 0, stream);
            if (p01 == 0)
                pre_gemm<<<ggrid, blk, 0, stream>>>(seqA, Wx + WLAYER,
                                                    bias + 2 * 4096, pre, 1024);
        }
    } else {
        // -------- fallback: EXACT R9 path (proven 6853us) --------
        float* seqB = reg2;
        unsigned short* hhi = hAhi;
        unsigned short* hlo = hAlo;
        for (int l = 0; l < 4; ++l) {
            const float* inp = (l == 0) ? x : ((l & 1) ? seqA : seqB);
            float* outp      = (l & 1) ? seqB : seqA;
            const float* wx  = (l == 0) ? Wx0 : (Wx + (size_t)(l - 1) * WLAYER);
            int K            = (l == 0) ? 256 : 1024;

            pre_gemm<<<ggrid, blk, 0, stream>>>(inp, wx, bias + (size_t)l * 4096, pre, K);

            const float* p = pre;
            const float* wh = Wh + (size_t)l * WLAYER;
            float* so = outp;
            int* pl1 = ctr + (size_t)l * PL;
            int last = (l == 3);
            void* args[] = { (void*)&p, (void*)&wh, (void*)&so, (void*)&hhi,
                             (void*)&hlo, (void*)&pl1, (void*)&fout, (void*)&last };
            hipLaunchCooperativeKernel((void*)lstm_scan, dim3(256), blk, args, 0, stream);
        }
    }
}